// Round 8
// baseline (161.796 us; speedup 1.0000x reference)
//
#include <hip/hip_runtime.h>
#include <hip/hip_bf16.h>
#include <stdint.h>

typedef __bf16 bf16;
typedef __bf16 bf16x8 __attribute__((ext_vector_type(8)));
typedef __bf16 bf16x4 __attribute__((ext_vector_type(4)));
typedef float  f32x4  __attribute__((ext_vector_type(4)));
typedef float  f32x16 __attribute__((ext_vector_type(16)));
typedef uint32_t u32;

#define MFMA16(a,b,c) __builtin_amdgcn_mfma_f32_16x16x32_bf16((a),(b),(c),0,0,0)
#define MFMA32(a,b,c) __builtin_amdgcn_mfma_f32_32x32x16_bf16((a),(b),(c),0,0,0)

// 0.125 (1/sqrt(64)) * log2(e): folded into Wq/bq so softmax runs in exp2 domain.
#define QSCL 0.1803368801111204f

// ---------- helpers ----------
__device__ __forceinline__ u32 sx32(u32 x) {  // value from lane^32 (HW-verified r3)
    return (u32)__shfl_xor((int)x, 32, 64);
}
__device__ __forceinline__ float swapred_max(float v) {
    return fmaxf(v, __builtin_bit_cast(float, sx32(__builtin_bit_cast(u32, v))));
}
__device__ __forceinline__ float swapred_sum(float v) {
    return v + __builtin_bit_cast(float, sx32(__builtin_bit_cast(u32, v)));
}
__device__ __forceinline__ u32 pkbf(float lo, float hi) {
    union { bf16 h[2]; u32 u; } un;
    un.h[0] = (bf16)lo; un.h[1] = (bf16)hi;
    return un.u;
}
// p[16] = exp'd scores for one 32-row K-block; lane (lm,hi) holds k_local(r) =
// (r&3) + 8*(r>>2) + 4*hi for col q=lm. Produce PV B-frags f0 (k=0..15) and
// f1 (k=16..31): lane needs k = 16*ks + hi*8 + j (j=0..7) at col q=lm.
__device__ __forceinline__ void pack_frags(const float* p, int hi, bf16x8& f0, bf16x8& f1) {
    u32 k01 = pkbf(p[0],  p[1]),  k23 = pkbf(p[2],  p[3]);
    u32 k45 = pkbf(p[4],  p[5]),  k67 = pkbf(p[6],  p[7]);
    u32 k89 = pkbf(p[8],  p[9]),  kab = pkbf(p[10], p[11]);
    u32 kcd = pkbf(p[12], p[13]), kef = pkbf(p[14], p[15]);
    u32 x01 = sx32(k01), x23 = sx32(k23), x45 = sx32(k45), x67 = sx32(k67);
    u32 x89 = sx32(k89), xab = sx32(kab), xcd = sx32(kcd), xef = sx32(kef);
    union { u32 w[4]; bf16x8 v; } u0, u1;
    u0.w[0] = hi ? x45 : k01;  u0.w[1] = hi ? x67 : k23;
    u0.w[2] = hi ? k45 : x01;  u0.w[3] = hi ? k67 : x23;
    u1.w[0] = hi ? xcd : k89;  u1.w[1] = hi ? xef : kab;
    u1.w[2] = hi ? kcd : x89;  u1.w[3] = hi ? kef : xab;
    f0 = u0.v; f1 = u1.v;
}

// ---------------- fp32 -> bf16 converts ----------------
__global__ __launch_bounds__(256) void k_cvt3(const float* __restrict__ a, const float* __restrict__ b,
                                              const float* __restrict__ c,
                                              bf16* __restrict__ x, bf16* __restrict__ y,
                                              bf16* __restrict__ z) {
    int i = blockIdx.x * 256 + threadIdx.x;          // vec4 index, 3 * 2^20 total
    int t = i >> 20;
    int r = (i & 1048575) << 2;
    const float* s = (t == 0) ? a : ((t == 1) ? b : c);
    bf16* d = (t == 0) ? x : ((t == 1) ? y : z);
    float4 v = *(const float4*)&s[r];
    bf16x4 w = {(bf16)v.x, (bf16)v.y, (bf16)v.z, (bf16)v.w};
    *(bf16x4*)&d[r] = w;
}
__global__ __launch_bounds__(256) void k_cvt1(const float* __restrict__ s, bf16* __restrict__ d) {
    int r = (blockIdx.x * 256 + threadIdx.x) << 2;
    float4 v = *(const float4*)&s[r];
    bf16x4 w = {(bf16)v.x, (bf16)v.y, (bf16)v.z, (bf16)v.w};
    *(bf16x4*)&d[r] = w;
}

// ---------------- weight transpose: W[k][n] fp32 -> Wt[n][k] bf16 (* scale) ----------------
__global__ __launch_bounds__(256) void k_transpose_w(const float* __restrict__ W,
                                                     bf16* __restrict__ Wt, float scale) {
    __shared__ bf16 t[64][65];
    const int n0 = blockIdx.x * 64, k0 = blockIdx.y * 64;
    for (int i = 0; i < 16; ++i) {
        int idx = threadIdx.x + i * 256, r = idx >> 6, c = idx & 63;
        t[r][c] = (bf16)(W[(size_t)(k0 + r) * 1024 + n0 + c] * scale);
    }
    __syncthreads();
    for (int i = 0; i < 16; ++i) {
        int idx = threadIdx.x + i * 256, r = idx >> 6, c = idx & 63;
        Wt[(size_t)(n0 + r) * 1024 + k0 + c] = t[c][r];
    }
}

// ---------------- V transpose: V[bh][s][d] -> Vt[bh][d][s] ----------------
__global__ __launch_bounds__(256) void k_transpose_v(const bf16* __restrict__ V,
                                                     bf16* __restrict__ Vt) {
    __shared__ bf16 t[64][65];
    const int s0 = blockIdx.x * 64, bh = blockIdx.y;
    for (int i = 0; i < 16; ++i) {
        int idx = threadIdx.x + i * 256, r = idx >> 6, c = idx & 63;
        t[r][c] = V[((size_t)bh * 2048 + s0 + r) * 64 + c];
    }
    __syncthreads();
    for (int i = 0; i < 16; ++i) {
        int idx = threadIdx.x + i * 256, r = idx >> 6, c = idx & 63;
        Vt[((size_t)bh * 64 + r) * 2048 + s0 + c] = t[c][r];
    }
}

// ---------------- GEMM tile body (m97 pattern) ----------------
__device__ __forceinline__ void gemm_tile(const bf16* __restrict__ A, const bf16* __restrict__ Bt,
                                          const float* __restrict__ bias, float bscale,
                                          void* __restrict__ Cp, int out_mode, int m0, int n0,
                                          bf16 (*As)[64], bf16 (*Bs)[64]) {
    const int tid = threadIdx.x;
    const int wid = tid >> 6, lane = tid & 63, lg = lane >> 4, lm = lane & 15;
    const int wr = wid >> 1, wc = wid & 1;
    const int grow = tid >> 3, gcol = (tid & 7) << 3;

    f32x4 acc[4][4] = {};

    for (int kt = 0; kt < 16; ++kt) {
        const int k0 = kt << 6;
        __syncthreads();
#pragma unroll
        for (int p = 0; p < 4; ++p) {
            __builtin_amdgcn_global_load_lds(
                (const __attribute__((address_space(1))) void*)(A + (size_t)(m0 + p * 32 + grow) * 1024 + k0 + gcol),
                (__attribute__((address_space(3))) void*)(&As[p * 32 + wid * 8][0]), 16, 0, 0);
            __builtin_amdgcn_global_load_lds(
                (const __attribute__((address_space(1))) void*)(Bt + (size_t)(n0 + p * 32 + grow) * 1024 + k0 + gcol),
                (__attribute__((address_space(3))) void*)(&Bs[p * 32 + wid * 8][0]), 16, 0, 0);
        }
        __syncthreads();
#pragma unroll
        for (int kk = 0; kk < 2; ++kk) {
            bf16x8 a[4], b[4];
#pragma unroll
            for (int i = 0; i < 4; ++i) a[i] = *(const bf16x8*)&As[wr * 64 + i * 16 + lm][kk * 32 + lg * 8];
#pragma unroll
            for (int j = 0; j < 4; ++j) b[j] = *(const bf16x8*)&Bs[wc * 64 + j * 16 + lm][kk * 32 + lg * 8];
#pragma unroll
            for (int i = 0; i < 4; ++i)
#pragma unroll
                for (int j = 0; j < 4; ++j) acc[i][j] = MFMA16(a[i], b[j], acc[i][j]);
        }
    }

    for (int i = 0; i < 4; ++i) {
        for (int j = 0; j < 4; ++j) {
            int col = n0 + wc * 64 + j * 16 + lm;
            float bv = bscale * bias[col];
            for (int q = 0; q < 4; ++q) {
                int row = m0 + wr * 64 + i * 16 + lg * 4 + q;
                float val = acc[i][j][q] + bv;
                if (out_mode == 0) {  // bf16 head layout [b][h][s][d]
                    int bb = row >> 11, s = row & 2047, h = col >> 6, d = col & 63;
                    ((bf16*)Cp)[(((size_t)bb * 16 + h) * 2048 + s) * 64 + d] = (bf16)val;
                } else {              // fp32 flat [M][N]
                    ((float*)Cp)[(size_t)row * 1024 + col] = (float)val;
                }
            }
        }
    }
}

// XCD-stripe decode: xcd owns m-tiles 4*xcd..4*xcd+3 (A stripe stays in its L2).
__device__ __forceinline__ void tile_decode(int r, int& m0, int& n0) {
    int xcd = r & 7, slot = (r >> 3) & 3, n = (r >> 5) & 7;
    m0 = (xcd * 4 + slot) * 128;
    n0 = n * 128;
}

__global__ __launch_bounds__(256, 4) void k_gemm_one(const bf16* __restrict__ A,
                                                     const bf16* __restrict__ Bt,
                                                     const float* __restrict__ bias, float bscale,
                                                     void* __restrict__ Cp, int out_mode) {
    __shared__ bf16 As[128][64];
    __shared__ bf16 Bs[128][64];
    int m0, n0;
    tile_decode(blockIdx.x, m0, n0);
    gemm_tile(A, Bt, bias, bscale, Cp, out_mode, m0, n0, As, Bs);
}

// fused Q/K/V projections: grid 768, z selects matrix (3 blocks/CU co-resident)
__global__ __launch_bounds__(256, 4) void k_gemm_qkv(const bf16* __restrict__ qc, const bf16* __restrict__ kc,
                                                     const bf16* __restrict__ vc,
                                                     const bf16* __restrict__ Wtq, const bf16* __restrict__ Wtk,
                                                     const bf16* __restrict__ Wtv,
                                                     const float* __restrict__ bq, const float* __restrict__ bk,
                                                     const float* __restrict__ bv,
                                                     bf16* __restrict__ Qb, bf16* __restrict__ Kb,
                                                     bf16* __restrict__ Vb) {
    __shared__ bf16 As[128][64];
    __shared__ bf16 Bs[128][64];
    int l = blockIdx.x, z = l >> 8, r = l & 255;
    int m0, n0;
    tile_decode(r, m0, n0);
    const bf16* A  = (z == 0) ? qc : ((z == 1) ? kc : vc);
    const bf16* Bt = (z == 0) ? Wtq : ((z == 1) ? Wtk : Wtv);
    const float* bias = (z == 0) ? bq : ((z == 1) ? bk : bv);
    float bscale = (z == 0) ? QSCL : 1.0f;
    bf16* Cp = (z == 0) ? Qb : ((z == 1) ? Kb : Vb);
    gemm_tile(A, Bt, bias, bscale, (void*)Cp, 0, m0, n0, As, Bs);
}

// ---------------- flash attention: 8-wave block, LDS-staged K/V, split-KV(2) ----------------
// Q,K: [bh][2048][64] bf16 (Q pre-scaled); Vt: [bh][64][2048].
// Block = 8 waves = 256 q-rows of one bh, keys [sp*1024, sp*1024+1024) in 64-key tiles.
// Grid = 32 bh x 8 qt x 2 sp = 512 blocks -> 2 co-resident 8-wave blocks/CU (16 waves).
// K(8KB)+Vt(8KB) per tile staged once via global_load_lds (double-buffered, 32KB LDS),
// XOR-swizzled via pre-swizzled SOURCE (linear dest + swz on read).
// Writes unnormalized O-partials (bf16, d_out scratch) + (m,l); k_combine merges.
__global__ __launch_bounds__(512, 4) void k_attn(const bf16* __restrict__ Q,
                                                 const bf16* __restrict__ Kb,
                                                 const bf16* __restrict__ Vt,
                                                 bf16* __restrict__ Opart,
                                                 float* __restrict__ ml) {
    __shared__ bf16 Ks[2][64 * 64];
    __shared__ bf16 Vs[2][64 * 64];
    const int tid = threadIdx.x;
    const int wid = tid >> 6, lane = tid & 63;
    const int lm = lane & 31, hi = lane >> 5;
    const int bid = blockIdx.x;
    const int bh = bid & 31, qt = (bid >> 5) & 7, sp = bid >> 8;  // bid%8==bh%8: XCD locality
    const int qrow = qt * 256 + wid * 32 + lm;
    const size_t qk_base = (size_t)bh * (2048 * 64);
    const size_t vt_base = (size_t)bh * (64 * 2048);
    const int kt0 = sp * 16, kt1 = kt0 + 16;

    // staging: thread t stages one 16B K-chunk + one 16B V-chunk per tile
    // (row = t>>3, chunk = t&7); source chunk pre-swizzled so
    // LDS[row][c] = global[row][c ^ (row&7)]
    const int srow = tid >> 3, sc8 = tid & 7;
    const int cse = (sc8 ^ (srow & 7)) * 8;          // source chunk, in elements
    const bf16* kstage = Kb + qk_base + (size_t)srow * 64 + cse;     // + kt*4096
    const bf16* vstage = Vt + vt_base + (size_t)srow * 2048 + cse;   // + kt*64
    const int ldsoff = wid * 1024;  // bytes; lanes scatter +lane*16 automatically

    // Q fragments (B operand): Q[qrow][f*16 + hi*8 .. +7], loaded once
    bf16x8 qf[4];
    {
        const bf16* qp = Q + qk_base + (size_t)qrow * 64 + hi * 8;
#pragma unroll
        for (int f = 0; f < 4; ++f) qf[f] = *(const bf16x8*)(qp + f * 16);
    }

    f32x16 O0 = {}, O1 = {};
    float mrow = -1e30f, lrow = 0.f;

    // read offsets (bytes) within an 8KB tile, swizzled: row*128 + (chunk^(row&7))*16
    const int swz = (lm & 7);

    // prologue: stage first tile
    __builtin_amdgcn_global_load_lds(
        (const __attribute__((address_space(1))) void*)(kstage + (size_t)kt0 * 4096),
        (__attribute__((address_space(3))) void*)((char*)&Ks[0][0] + ldsoff), 16, 0, 0);
    __builtin_amdgcn_global_load_lds(
        (const __attribute__((address_space(1))) void*)(vstage + (size_t)kt0 * 64),
        (__attribute__((address_space(3))) void*)((char*)&Vs[0][0] + ldsoff), 16, 0, 0);
    __syncthreads();

    int cur = 0;
#pragma unroll 1
    for (int kt = kt0; kt < kt1; ++kt) {
        // stage next tile into buf[cur^1] (overlaps with compute below)
        if (kt + 1 < kt1) {
            __builtin_amdgcn_global_load_lds(
                (const __attribute__((address_space(1))) void*)(kstage + (size_t)(kt + 1) * 4096),
                (__attribute__((address_space(3))) void*)((char*)&Ks[cur ^ 1][0] + ldsoff), 16, 0, 0);
            __builtin_amdgcn_global_load_lds(
                (const __attribute__((address_space(1))) void*)(vstage + (size_t)(kt + 1) * 64),
                (__attribute__((address_space(3))) void*)((char*)&Vs[cur ^ 1][0] + ldsoff), 16, 0, 0);
        }

        const char* Ksc = (const char*)&Ks[cur][0];
        const char* Vsc = (const char*)&Vs[cur][0];

        // K frags (A operand): key rows lm / lm+32, d = f*16 + hi*8
        bf16x8 kf0[4], kf1[4];
#pragma unroll
        for (int f = 0; f < 4; ++f) {
            int ch = (f << 1) | hi;
            kf0[f] = *(const bf16x8*)(Ksc + lm * 128 + ((ch ^ swz) << 4));
            kf1[f] = *(const bf16x8*)(Ksc + (lm + 32) * 128 + ((ch ^ swz) << 4));
        }
        // V frags (A operand for O^T): d rows lm / lm+32, key = ks*16 + hi*8
        bf16x8 vf0[4], vf1[4];
#pragma unroll
        for (int ks = 0; ks < 4; ++ks) {
            int ch = (ks << 1) | hi;
            vf0[ks] = *(const bf16x8*)(Vsc + lm * 128 + ((ch ^ swz) << 4));
            vf1[ks] = *(const bf16x8*)(Vsc + (lm + 32) * 128 + ((ch ^ swz) << 4));
        }

        // S^T = K · Q^T  (col = q = lm, row = k_local = (reg&3)+8*(reg>>2)+4*hi)
        f32x16 s0 = {}, s1 = {};
#pragma unroll
        for (int f = 0; f < 4; ++f) {
            s0 = MFMA32(kf0[f], qf[f], s0);
            s1 = MFMA32(kf1[f], qf[f], s1);
        }

        // tile row-max (tree + cross-half swap)
        float t8[8];
#pragma unroll
        for (int r = 0; r < 8; ++r)
            t8[r] = fmaxf(fmaxf(s0[r], s0[r + 8]), fmaxf(s1[r], s1[r + 8]));
#pragma unroll
        for (int st = 4; st; st >>= 1)
#pragma unroll
            for (int r = 0; r < st; ++r) t8[r] = fmaxf(t8[r], t8[r + st]);
        float pm = swapred_max(t8[0]);

        // defer-max: rescale only when running max grew by > 8 (exp2 domain)
        if (!__all(pm <= mrow + 8.0f)) {
            float mnew = fmaxf(mrow, pm);
            float corr = __builtin_amdgcn_exp2f(mrow - mnew);
            lrow *= corr;
            O0 *= corr;
            O1 *= corr;
            mrow = mnew;
        }

        // P = exp2(S - m)
        float p0a[16], p1a[16];
#pragma unroll
        for (int r = 0; r < 16; ++r) p0a[r] = __builtin_amdgcn_exp2f(s0[r] - mrow);
#pragma unroll
        for (int r = 0; r < 16; ++r) p1a[r] = __builtin_amdgcn_exp2f(s1[r] - mrow);
        float u8[8];
#pragma unroll
        for (int r = 0; r < 8; ++r) u8[r] = (p0a[r] + p0a[r + 8]) + (p1a[r] + p1a[r + 8]);
#pragma unroll
        for (int st = 4; st; st >>= 1)
#pragma unroll
            for (int r = 0; r < st; ++r) u8[r] = u8[r] + u8[r + st];
        lrow += swapred_sum(u8[0]);

        // redistribute P into PV B-frags (in-register, shfl_xor 32)
        bf16x8 pf[4];
        pack_frags(p0a, hi, pf[0], pf[1]);
        pack_frags(p1a, hi, pf[2], pf[3]);

        // O^T += Vt · P^T
#pragma unroll
        for (int ks = 0; ks < 4; ++ks) {
            O0 = MFMA32(vf0[ks], pf[ks], O0);
            O1 = MFMA32(vf1[ks], pf[ks], O1);
        }

        // drain next-tile stage + release buf[cur] reads
        __syncthreads();
        cur ^= 1;
    }

    // write unnormalized partials + (m,l)
    const size_t r2 = ((size_t)bh * 2048 + qrow) * 2 + sp;
    bf16* op = Opart + r2 * 64 + 4 * hi;
#pragma unroll
    for (int t = 0; t < 4; ++t) {
        bf16x4 w0, w1;
#pragma unroll
        for (int e = 0; e < 4; ++e) {
            w0[e] = (bf16)O0[4 * t + e];
            w1[e] = (bf16)O1[4 * t + e];
        }
        *(bf16x4*)(op + 8 * t)      = w0;   // d = 4*hi + 8*t + e
        *(bf16x4*)(op + 32 + 8 * t) = w1;   // + 32
    }
    if (hi == 0) {
        float2 v = {mrow, lrow};
        ((float2*)ml)[r2] = v;
    }
}

// ---------------- combine: merge 2 split partials -> AOb [b][s][h*64+d] bf16 ----------------
__global__ __launch_bounds__(256) void k_combine(const bf16* __restrict__ Opart,
                                                 const float* __restrict__ ml,
                                                 bf16* __restrict__ AOb) {
    int e8 = blockIdx.x * 256 + threadIdx.x;   // 524288 total
    int row = e8 >> 3, dc = (e8 & 7) << 3;
    float2 ml0 = ((const float2*)ml)[row * 2 + 0];
    float2 ml1 = ((const float2*)ml)[row * 2 + 1];
    float M  = fmaxf(ml0.x, ml1.x);
    float w0 = __builtin_amdgcn_exp2f(ml0.x - M);
    float w1 = __builtin_amdgcn_exp2f(ml1.x - M);
    float L  = w0 * ml0.y + w1 * ml1.y;
    float a0 = w0 / L, a1 = w1 / L;
    bf16x8 p0 = *(const bf16x8*)&Opart[((size_t)row * 2 + 0) * 64 + dc];
    bf16x8 p1 = *(const bf16x8*)&Opart[((size_t)row * 2 + 1) * 64 + dc];
    bf16x8 o;
#pragma unroll
    for (int j = 0; j < 8; ++j) o[j] = (bf16)(a0 * (float)p0[j] + a1 * (float)p1[j]);
    int bh = row >> 11, qrow = row & 2047;
    int bb = bh >> 4, h = bh & 15;
    *(bf16x8*)&AOb[((size_t)bb * 2048 + qrow) * 1024 + h * 64 + dc] = o;
}

extern "C" void kernel_launch(void* const* d_in, const int* in_sizes, int n_in,
                              void* d_out, int out_size, void* d_ws, size_t ws_size,
                              hipStream_t stream) {
    const float* q  = (const float*)d_in[0];
    const float* k  = (const float*)d_in[1];
    const float* v  = (const float*)d_in[2];
    const float* Wq = (const float*)d_in[3];
    const float* bq = (const float*)d_in[4];
    const float* Wk = (const float*)d_in[5];
    const float* bk = (const float*)d_in[6];
    const float* Wv = (const float*)d_in[7];
    const float* bv = (const float*)d_in[8];
    const float* Wo = (const float*)d_in[9];
    const float* bo = (const float*)d_in[10];

    char* ws = (char*)d_ws;
    const size_t MB = 1ull << 20;
    const dim3 twg(16, 16), blk(256);
    bf16* Opart = (bf16*)d_out;   // 16.78 MB scratch until the final GEMM (exact fit)

    if (ws_size >= 64 * MB) {
        // fused path (64 MB)
        bf16* Wtq = (bf16*)(ws + 0 * MB);
        bf16* Wtk = (bf16*)(ws + 2 * MB);
        bf16* Wtv = (bf16*)(ws + 4 * MB);
        bf16* Wto = (bf16*)(ws + 6 * MB);
        bf16* qc  = (bf16*)(ws + 8 * MB);
        bf16* kc  = (bf16*)(ws + 16 * MB);
        bf16* vc  = (bf16*)(ws + 24 * MB);
        bf16* Qb  = (bf16*)(ws + 32 * MB);
        bf16* Kb  = (bf16*)(ws + 40 * MB);
        bf16* Vb  = (bf16*)(ws + 48 * MB);
        bf16* Vtb = (bf16*)(ws + 56 * MB);
        float* mlb = (float*)qc;  // qc free after QKV gemm
        bf16* AOb  = kc;          // kc free after QKV gemm

        k_transpose_w<<<twg, blk, 0, stream>>>(Wq, Wtq, QSCL);
        k_transpose_w<<<twg, blk, 0, stream>>>(Wk, Wtk, 1.0f);
        k_transpose_w<<<twg, blk, 0, stream>>>(Wv, Wtv, 1.0f);
        k_transpose_w<<<twg, blk, 0, stream>>>(Wo, Wto, 1.0f);
        k_cvt3<<<12288, blk, 0, stream>>>(q, k, v, qc, kc, vc);
        k_gemm_qkv<<<768, blk, 0, stream>>>(qc, kc, vc, Wtq, Wtk, Wtv, bq, bk, bv, Qb, Kb, Vb);
        k_transpose_v<<<dim3(32, 32), blk, 0, stream>>>(Vb, Vtb);
        k_attn<<<512, 512, 0, stream>>>(Qb, Kb, Vtb, Opart, mlb);
        k_combine<<<2048, blk, 0, stream>>>(Opart, mlb, AOb);
        k_gemm_one<<<256, blk, 0, stream>>>(AOb, Wto, bo, 1.0f, d_out, 1);
    } else {
        // sequential fallback (27 MB ws + d_out scratch)
        bf16* Wt   = (bf16*)(ws + 0 * MB);
        bf16* Qb   = (bf16*)(ws + 2 * MB);
        bf16* Kb   = (bf16*)(ws + 10 * MB);
        bf16* Vtb  = (bf16*)(ws + 18 * MB);
        float* mlb = (float*)(ws + 26 * MB);
        bf16* Cb   = Vtb;              // cvt scratch until transpose_v
        bf16* Vb   = (bf16*)d_out;     // V materializes in d_out, dead after transpose_v
        bf16* AOb  = Qb;               // Qb dead after attn

        k_cvt1<<<4096, blk, 0, stream>>>(q, Cb);
        k_transpose_w<<<twg, blk, 0, stream>>>(Wq, Wt, QSCL);
        k_gemm_one<<<256, blk, 0, stream>>>(Cb, Wt, bq, QSCL, (void*)Qb, 0);
        k_cvt1<<<4096, blk, 0, stream>>>(k, Cb);
        k_transpose_w<<<twg, blk, 0, stream>>>(Wk, Wt, 1.0f);
        k_gemm_one<<<256, blk, 0, stream>>>(Cb, Wt, bk, 1.0f, (void*)Kb, 0);
        k_cvt1<<<4096, blk, 0, stream>>>(v, Cb);
        k_transpose_w<<<twg, blk, 0, stream>>>(Wv, Wt, 1.0f);
        k_gemm_one<<<256, blk, 0, stream>>>(Cb, Wt, bv, 1.0f, (void*)Vb, 0);
        k_transpose_v<<<dim3(32, 32), blk, 0, stream>>>(Vb, Vtb);
        k_transpose_w<<<twg, blk, 0, stream>>>(Wo, Wt, 1.0f);
        k_attn<<<512, 512, 0, stream>>>(Qb, Kb, Vtb, Opart, mlb);
        k_combine<<<2048, blk, 0, stream>>>(Opart, mlb, AOb);
        k_gemm_one<<<256, blk, 0, stream>>>(AOb, Wt, bo, 1.0f, d_out, 1);
    }
}

// Round 9
// 144.227 us; speedup vs baseline: 1.1218x; 1.1218x over previous
//
#include <hip/hip_runtime.h>
#include <hip/hip_bf16.h>
#include <stdint.h>

typedef __bf16 bf16;
typedef __bf16 bf16x8 __attribute__((ext_vector_type(8)));
typedef __bf16 bf16x4 __attribute__((ext_vector_type(4)));
typedef float  f32x4  __attribute__((ext_vector_type(4)));
typedef float  f32x16 __attribute__((ext_vector_type(16)));
typedef uint32_t u32;

#define MFMA16(a,b,c) __builtin_amdgcn_mfma_f32_16x16x32_bf16((a),(b),(c),0,0,0)
#define MFMA32(a,b,c) __builtin_amdgcn_mfma_f32_32x32x16_bf16((a),(b),(c),0,0,0)

// 0.125 (1/sqrt(64)) * log2(e): folded into Wq/bq so softmax runs in exp2 domain.
#define QSCL 0.1803368801111204f

// ---------- helpers ----------
__device__ __forceinline__ u32 sx32(u32 x) {  // value from lane^32 (HW-verified r3)
    return (u32)__shfl_xor((int)x, 32, 64);
}
__device__ __forceinline__ float swapred_max(float v) {
    return fmaxf(v, __builtin_bit_cast(float, sx32(__builtin_bit_cast(u32, v))));
}
__device__ __forceinline__ float swapred_sum(float v) {
    return v + __builtin_bit_cast(float, sx32(__builtin_bit_cast(u32, v)));
}
__device__ __forceinline__ u32 pkbf(float lo, float hi) {
    union { bf16 h[2]; u32 u; } un;
    un.h[0] = (bf16)lo; un.h[1] = (bf16)hi;
    return un.u;
}
// p[16] = exp'd scores for one 32-row K-block; lane (lm,hi) holds k_local(r) =
// (r&3) + 8*(r>>2) + 4*hi for col q=lm. Produce PV B-frags f0 (k=0..15) and
// f1 (k=16..31): lane needs k = 16*ks + hi*8 + j (j=0..7) at col q=lm.
__device__ __forceinline__ void pack_frags(const float* p, int hi, bf16x8& f0, bf16x8& f1) {
    u32 k01 = pkbf(p[0],  p[1]),  k23 = pkbf(p[2],  p[3]);
    u32 k45 = pkbf(p[4],  p[5]),  k67 = pkbf(p[6],  p[7]);
    u32 k89 = pkbf(p[8],  p[9]),  kab = pkbf(p[10], p[11]);
    u32 kcd = pkbf(p[12], p[13]), kef = pkbf(p[14], p[15]);
    u32 x01 = sx32(k01), x23 = sx32(k23), x45 = sx32(k45), x67 = sx32(k67);
    u32 x89 = sx32(k89), xab = sx32(kab), xcd = sx32(kcd), xef = sx32(kef);
    union { u32 w[4]; bf16x8 v; } u0, u1;
    u0.w[0] = hi ? x45 : k01;  u0.w[1] = hi ? x67 : k23;
    u0.w[2] = hi ? k45 : x01;  u0.w[3] = hi ? k67 : x23;
    u1.w[0] = hi ? xcd : k89;  u1.w[1] = hi ? xef : kab;
    u1.w[2] = hi ? kcd : x89;  u1.w[3] = hi ? kef : xab;
    f0 = u0.v; f1 = u1.v;
}

// ---------------- fp32 -> bf16 converts ----------------
__global__ __launch_bounds__(256) void k_cvt3(const float* __restrict__ a, const float* __restrict__ b,
                                              const float* __restrict__ c,
                                              bf16* __restrict__ x, bf16* __restrict__ y,
                                              bf16* __restrict__ z) {
    int i = blockIdx.x * 256 + threadIdx.x;          // vec4 index, 3 * 2^20 total
    int t = i >> 20;
    int r = (i & 1048575) << 2;
    const float* s = (t == 0) ? a : ((t == 1) ? b : c);
    bf16* d = (t == 0) ? x : ((t == 1) ? y : z);
    float4 v = *(const float4*)&s[r];
    bf16x4 w = {(bf16)v.x, (bf16)v.y, (bf16)v.z, (bf16)v.w};
    *(bf16x4*)&d[r] = w;
}
__global__ __launch_bounds__(256) void k_cvt1(const float* __restrict__ s, bf16* __restrict__ d) {
    int r = (blockIdx.x * 256 + threadIdx.x) << 2;
    float4 v = *(const float4*)&s[r];
    bf16x4 w = {(bf16)v.x, (bf16)v.y, (bf16)v.z, (bf16)v.w};
    *(bf16x4*)&d[r] = w;
}

// ---------------- weight transpose: W[k][n] fp32 -> Wt[n][k] bf16 (* scale) ----------------
__global__ __launch_bounds__(256) void k_transpose_w(const float* __restrict__ W,
                                                     bf16* __restrict__ Wt, float scale) {
    __shared__ bf16 t[64][65];
    const int n0 = blockIdx.x * 64, k0 = blockIdx.y * 64;
    for (int i = 0; i < 16; ++i) {
        int idx = threadIdx.x + i * 256, r = idx >> 6, c = idx & 63;
        t[r][c] = (bf16)(W[(size_t)(k0 + r) * 1024 + n0 + c] * scale);
    }
    __syncthreads();
    for (int i = 0; i < 16; ++i) {
        int idx = threadIdx.x + i * 256, r = idx >> 6, c = idx & 63;
        Wt[(size_t)(n0 + r) * 1024 + k0 + c] = t[c][r];
    }
}

// ---------------- GEMM tile body (m97 pattern), 128x128, K=1024 ----------------
// out_mode 0: bf16 head layout [b][h][s][d] (proj Q/K; A=activation, Bt=weight)
// out_mode 2: bf16 Vt layout [bh][d][s]     (A=weight rows=h*64+d, Bt=activation rows=s)
__device__ __forceinline__ void gemm_tile(const bf16* __restrict__ A, const bf16* __restrict__ Bt,
                                          const float* __restrict__ bias, float bscale,
                                          void* __restrict__ Cp, int out_mode, int m0, int n0,
                                          bf16 (*As)[64], bf16 (*Bs)[64]) {
    const int tid = threadIdx.x;
    const int wid = tid >> 6, lane = tid & 63, lg = lane >> 4, lm = lane & 15;
    const int wr = wid >> 1, wc = wid & 1;
    const int grow = tid >> 3, gcol = (tid & 7) << 3;

    f32x4 acc[4][4] = {};

    for (int kt = 0; kt < 16; ++kt) {
        const int k0 = kt << 6;
        __syncthreads();
#pragma unroll
        for (int p = 0; p < 4; ++p) {
            __builtin_amdgcn_global_load_lds(
                (const __attribute__((address_space(1))) void*)(A + (size_t)(m0 + p * 32 + grow) * 1024 + k0 + gcol),
                (__attribute__((address_space(3))) void*)(&As[p * 32 + wid * 8][0]), 16, 0, 0);
            __builtin_amdgcn_global_load_lds(
                (const __attribute__((address_space(1))) void*)(Bt + (size_t)(n0 + p * 32 + grow) * 1024 + k0 + gcol),
                (__attribute__((address_space(3))) void*)(&Bs[p * 32 + wid * 8][0]), 16, 0, 0);
        }
        __syncthreads();
#pragma unroll
        for (int kk = 0; kk < 2; ++kk) {
            bf16x8 a[4], b[4];
#pragma unroll
            for (int i = 0; i < 4; ++i) a[i] = *(const bf16x8*)&As[wr * 64 + i * 16 + lm][kk * 32 + lg * 8];
#pragma unroll
            for (int j = 0; j < 4; ++j) b[j] = *(const bf16x8*)&Bs[wc * 64 + j * 16 + lm][kk * 32 + lg * 8];
#pragma unroll
            for (int i = 0; i < 4; ++i)
#pragma unroll
                for (int j = 0; j < 4; ++j) acc[i][j] = MFMA16(a[i], b[j], acc[i][j]);
        }
    }

    for (int i = 0; i < 4; ++i) {
        for (int j = 0; j < 4; ++j) {
            int col = n0 + wc * 64 + j * 16 + lm;
            for (int q = 0; q < 4; ++q) {
                int row = m0 + wr * 64 + i * 16 + lg * 4 + q;
                if (out_mode == 0) {  // bf16 head layout [b][h][s][d]
                    float val = acc[i][j][q] + bscale * bias[col];
                    int bb = row >> 11, s = row & 2047, h = col >> 6, d = col & 63;
                    ((bf16*)Cp)[(((size_t)bb * 16 + h) * 2048 + s) * 64 + d] = (bf16)val;
                } else {              // Vt layout [bh][d][s], bias per ROW
                    float val = acc[i][j][q] + bias[row];
                    size_t idx = (((size_t)(col >> 11) * 16 + (row >> 6)) * 64 + (row & 63)) * 2048 + (col & 2047);
                    ((bf16*)Cp)[idx] = (bf16)val;
                }
            }
        }
    }
}

// XCD-stripe decode for M=4096,N=1024: xcd owns m-tiles 4*xcd..4*xcd+3.
__device__ __forceinline__ void tile_decode(int r, int& m0, int& n0) {
    int xcd = r & 7, slot = (r >> 3) & 3, n = (r >> 5) & 7;
    m0 = (xcd * 4 + slot) * 128;
    n0 = n * 128;
}
// decode for Vt gemm (M=1024 weight-rows, N=4096 seq): xcd owns 4 n-tiles.
__device__ __forceinline__ void tile_decode_vt(int r, int& m0, int& n0) {
    int xcd = r & 7, loc = r >> 3;       // loc in [0,32)
    int nslot = loc & 3, m = loc >> 2;   // m in [0,8)
    n0 = (xcd * 4 + nslot) * 128;
    m0 = m * 128;
}

__global__ __launch_bounds__(256, 4) void k_gemm_proj(const bf16* __restrict__ A,
                                                      const bf16* __restrict__ Bt,
                                                      const float* __restrict__ bias, float bscale,
                                                      void* __restrict__ Cp) {
    __shared__ bf16 As[128][64];
    __shared__ bf16 Bs[128][64];
    int m0, n0;
    tile_decode(blockIdx.x, m0, n0);
    gemm_tile(A, Bt, bias, bscale, Cp, 0, m0, n0, As, Bs);
}

__global__ __launch_bounds__(256, 4) void k_gemm_vt(const bf16* __restrict__ Wtv,
                                                    const bf16* __restrict__ vc,
                                                    const float* __restrict__ bias,
                                                    bf16* __restrict__ Vtb) {
    __shared__ bf16 As[128][64];
    __shared__ bf16 Bs[128][64];
    int m0, n0;
    tile_decode_vt(blockIdx.x, m0, n0);
    gemm_tile(Wtv, vc, bias, 1.0f, (void*)Vtb, 2, m0, n0, As, Bs);
}

// fused Q/K/V projections: grid 768, z selects matrix (3 blocks/CU co-resident)
__global__ __launch_bounds__(256, 4) void k_gemm_qkv(const bf16* __restrict__ qc, const bf16* __restrict__ kc,
                                                     const bf16* __restrict__ vc,
                                                     const bf16* __restrict__ Wtq, const bf16* __restrict__ Wtk,
                                                     const bf16* __restrict__ Wtv,
                                                     const float* __restrict__ bq, const float* __restrict__ bk,
                                                     const float* __restrict__ bv,
                                                     bf16* __restrict__ Qb, bf16* __restrict__ Kb,
                                                     bf16* __restrict__ Vtb) {
    __shared__ bf16 As[128][64];
    __shared__ bf16 Bs[128][64];
    int l = blockIdx.x, z = l >> 8, r = l & 255;
    int m0, n0;
    if (z == 2) {
        tile_decode_vt(r, m0, n0);
        gemm_tile(Wtv, vc, bv, 1.0f, (void*)Vtb, 2, m0, n0, As, Bs);
    } else {
        tile_decode(r, m0, n0);
        const bf16* A  = (z == 0) ? qc : kc;
        const bf16* Bt = (z == 0) ? Wtq : Wtk;
        const float* bias = (z == 0) ? bq : bk;
        float bscale = (z == 0) ? QSCL : 1.0f;
        bf16* Cp = (z == 0) ? Qb : Kb;
        gemm_tile(A, Bt, bias, bscale, (void*)Cp, 0, m0, n0, As, Bs);
    }
}

// ---------------- output projection: 128x64 tiles, 512 blocks (2/CU) ----------------
// C[4096][1024] fp32 = A[4096][1024]bf16 @ Wto[1024][1024]bf16^T + bo
__global__ __launch_bounds__(256, 4) void k_gemm_out(const bf16* __restrict__ A,
                                                     const bf16* __restrict__ Bt,
                                                     const float* __restrict__ bias,
                                                     float* __restrict__ C) {
    __shared__ bf16 As[128][64];
    __shared__ bf16 Bs[64][64];
    const int tid = threadIdx.x;
    const int wid = tid >> 6, lane = tid & 63, lg = lane >> 4, lm = lane & 15;
    const int grow = tid >> 3, gcol = (tid & 7) << 3;
    // decode: xcd owns m-tiles 4x..4x+3 (A stripe + Wto stay L2-resident)
    const int r = blockIdx.x;
    const int xcd = r & 7, loc = r >> 3;          // loc in [0,64)
    const int mslot = loc & 3, n = loc >> 2;      // n in [0,16)
    const int m0 = (xcd * 4 + mslot) * 128, n0 = n * 64;

    f32x4 acc[2][4] = {};

    for (int kt = 0; kt < 16; ++kt) {
        const int k0 = kt << 6;
        __syncthreads();
#pragma unroll
        for (int p = 0; p < 4; ++p)
            __builtin_amdgcn_global_load_lds(
                (const __attribute__((address_space(1))) void*)(A + (size_t)(m0 + p * 32 + grow) * 1024 + k0 + gcol),
                (__attribute__((address_space(3))) void*)(&As[p * 32 + wid * 8][0]), 16, 0, 0);
#pragma unroll
        for (int p = 0; p < 2; ++p)
            __builtin_amdgcn_global_load_lds(
                (const __attribute__((address_space(1))) void*)(Bt + (size_t)(n0 + p * 32 + grow) * 1024 + k0 + gcol),
                (__attribute__((address_space(3))) void*)(&Bs[p * 32 + wid * 8][0]), 16, 0, 0);
        __syncthreads();
#pragma unroll
        for (int kk = 0; kk < 2; ++kk) {
            bf16x8 a[2], b[4];
#pragma unroll
            for (int i = 0; i < 2; ++i) a[i] = *(const bf16x8*)&As[wid * 32 + i * 16 + lm][kk * 32 + lg * 8];
#pragma unroll
            for (int j = 0; j < 4; ++j) b[j] = *(const bf16x8*)&Bs[j * 16 + lm][kk * 32 + lg * 8];
#pragma unroll
            for (int i = 0; i < 2; ++i)
#pragma unroll
                for (int j = 0; j < 4; ++j) acc[i][j] = MFMA16(a[i], b[j], acc[i][j]);
        }
    }

    for (int i = 0; i < 2; ++i) {
        for (int j = 0; j < 4; ++j) {
            int col = n0 + j * 16 + lm;
            float bv = bias[col];
            for (int q = 0; q < 4; ++q) {
                int row = m0 + wid * 32 + i * 16 + lg * 4 + q;
                C[(size_t)row * 1024 + col] = acc[i][j][q] + bv;
            }
        }
    }
}

// ---------------- flash attention: 8-wave block, LDS-staged K/V (R6 base) ----------------
// + speculative exp (overlaps max-tree latency) + deferred cross-half l-sum.
// Q,K: [bh][2048][64] bf16 (Q pre-scaled); Vt: [bh][64][2048]; Out: [b][s][h*64+d] bf16.
__global__ __launch_bounds__(512, 2) void k_attn(const bf16* __restrict__ Q,
                                                 const bf16* __restrict__ Kb,
                                                 const bf16* __restrict__ Vt,
                                                 bf16* __restrict__ Out) {
    __shared__ bf16 Ks[2][64 * 64];
    __shared__ bf16 Vs[2][64 * 64];
    const int tid = threadIdx.x;
    const int wid = tid >> 6, lane = tid & 63;
    const int lm = lane & 31, hi = lane >> 5;
    const int bid = blockIdx.x;
    const int bh = bid & 31, qt = bid >> 5;   // same-bh blocks share an XCD's L2
    const int bb = bh >> 4, h = bh & 15;
    const int qrow = qt * 256 + wid * 32 + lm;
    const size_t qk_base = (size_t)bh * (2048 * 64);
    const size_t vt_base = (size_t)bh * (64 * 2048);

    // staging geometry (proven r6): LDS[row][c] = global[row][c ^ (row&7)] via source swizzle
    const int srow = tid >> 3, sc8 = tid & 7;
    const int cse = (sc8 ^ (srow & 7)) * 8;
    const bf16* kstage = Kb + qk_base + (size_t)srow * 64 + cse;     // + kt*4096
    const bf16* vstage = Vt + vt_base + (size_t)srow * 2048 + cse;   // + kt*64
    const int ldsoff = wid * 1024;

    bf16x8 qf[4];
    {
        const bf16* qp = Q + qk_base + (size_t)qrow * 64 + hi * 8;
#pragma unroll
        for (int f = 0; f < 4; ++f) qf[f] = *(const bf16x8*)(qp + f * 16);
    }

    f32x16 O0 = {}, O1 = {};
    float mrow = -1e30f, lsum = 0.f;   // lsum = this lane's half; cross-half sum deferred

    const int swz = (lm & 7);

    __builtin_amdgcn_global_load_lds(
        (const __attribute__((address_space(1))) void*)(kstage),
        (__attribute__((address_space(3))) void*)((char*)&Ks[0][0] + ldsoff), 16, 0, 0);
    __builtin_amdgcn_global_load_lds(
        (const __attribute__((address_space(1))) void*)(vstage),
        (__attribute__((address_space(3))) void*)((char*)&Vs[0][0] + ldsoff), 16, 0, 0);
    __syncthreads();

    int cur = 0;
#pragma unroll 1
    for (int kt = 0; kt < 32; ++kt) {
        if (kt + 1 < 32) {
            __builtin_amdgcn_global_load_lds(
                (const __attribute__((address_space(1))) void*)(kstage + (size_t)(kt + 1) * 4096),
                (__attribute__((address_space(3))) void*)((char*)&Ks[cur ^ 1][0] + ldsoff), 16, 0, 0);
            __builtin_amdgcn_global_load_lds(
                (const __attribute__((address_space(1))) void*)(vstage + (size_t)(kt + 1) * 64),
                (__attribute__((address_space(3))) void*)((char*)&Vs[cur ^ 1][0] + ldsoff), 16, 0, 0);
        }

        const char* Ksc = (const char*)&Ks[cur][0];
        const char* Vsc = (const char*)&Vs[cur][0];

        bf16x8 kf0[4], kf1[4];
#pragma unroll
        for (int f = 0; f < 4; ++f) {
            int ch = (f << 1) | hi;
            kf0[f] = *(const bf16x8*)(Ksc + lm * 128 + ((ch ^ swz) << 4));
            kf1[f] = *(const bf16x8*)(Ksc + (lm + 32) * 128 + ((ch ^ swz) << 4));
        }
        bf16x8 vf0[4], vf1[4];
#pragma unroll
        for (int ks = 0; ks < 4; ++ks) {
            int ch = (ks << 1) | hi;
            vf0[ks] = *(const bf16x8*)(Vsc + lm * 128 + ((ch ^ swz) << 4));
            vf1[ks] = *(const bf16x8*)(Vsc + (lm + 32) * 128 + ((ch ^ swz) << 4));
        }

        // S^T = K · Q^T
        f32x16 s0 = {}, s1 = {};
#pragma unroll
        for (int f = 0; f < 4; ++f) {
            s0 = MFMA32(kf0[f], qf[f], s0);
            s1 = MFMA32(kf1[f], qf[f], s1);
        }

        // speculative P = exp2(S - mrow_old): starts immediately, overlaps max reduction
        float pe0[16], pe1[16];
#pragma unroll
        for (int r = 0; r < 16; ++r) pe0[r] = __builtin_amdgcn_exp2f(s0[r] - mrow);
#pragma unroll
        for (int r = 0; r < 16; ++r) pe1[r] = __builtin_amdgcn_exp2f(s1[r] - mrow);

        // tile row-max (tree + cross-half swap)
        float t8[8];
#pragma unroll
        for (int r = 0; r < 8; ++r)
            t8[r] = fmaxf(fmaxf(s0[r], s0[r + 8]), fmaxf(s1[r], s1[r + 8]));
#pragma unroll
        for (int st = 4; st; st >>= 1)
#pragma unroll
            for (int r = 0; r < st; ++r) t8[r] = fmaxf(t8[r], t8[r + st]);
        float pm = swapred_max(t8[0]);

        // defer-max: rescale (and redo exp with the new max) only when max grew > 8
        if (!__all(pm <= mrow + 8.0f)) {
            float mnew = fmaxf(mrow, pm);
            float corr = __builtin_amdgcn_exp2f(mrow - mnew);
            lsum *= corr;
            O0 *= corr;
            O1 *= corr;
            mrow = mnew;
#pragma unroll
            for (int r = 0; r < 16; ++r) pe0[r] = __builtin_amdgcn_exp2f(s0[r] - mrow);
#pragma unroll
            for (int r = 0; r < 16; ++r) pe1[r] = __builtin_amdgcn_exp2f(s1[r] - mrow);
        }

        // lane-local row-sum (cross-half swap deferred to epilogue)
        float u8[8];
#pragma unroll
        for (int r = 0; r < 8; ++r) u8[r] = (pe0[r] + pe0[r + 8]) + (pe1[r] + pe1[r + 8]);
#pragma unroll
        for (int st = 4; st; st >>= 1)
#pragma unroll
            for (int r = 0; r < st; ++r) u8[r] = u8[r] + u8[r + st];
        lsum += u8[0];

        // redistribute P into PV B-frags (in-register, shfl_xor 32)
        bf16x8 pf[4];
        pack_frags(pe0, hi, pf[0], pf[1]);
        pack_frags(pe1, hi, pf[2], pf[3]);

        // O^T += Vt · P^T
#pragma unroll
        for (int ks = 0; ks < 4; ++ks) {
            O0 = MFMA32(vf0[ks], pf[ks], O0);
            O1 = MFMA32(vf1[ks], pf[ks], O1);
        }

        __syncthreads();
        cur ^= 1;
    }

    float lrow = swapred_sum(lsum);
    float inv = 1.0f / lrow;
    bf16* op = Out + ((size_t)bb * 2048 + qrow) * 1024 + h * 64 + 4 * hi;
#pragma unroll
    for (int t = 0; t < 4; ++t) {
        bf16x4 w0, w1;
#pragma unroll
        for (int e = 0; e < 4; ++e) {
            w0[e] = (bf16)(O0[4 * t + e] * inv);
            w1[e] = (bf16)(O1[4 * t + e] * inv);
        }
        *(bf16x4*)(op + 8 * t)      = w0;   // d = 4*hi + 8*t + e
        *(bf16x4*)(op + 32 + 8 * t) = w1;   // + 32
    }
}

extern "C" void kernel_launch(void* const* d_in, const int* in_sizes, int n_in,
                              void* d_out, int out_size, void* d_ws, size_t ws_size,
                              hipStream_t stream) {
    const float* q  = (const float*)d_in[0];
    const float* k  = (const float*)d_in[1];
    const float* v  = (const float*)d_in[2];
    const float* Wq = (const float*)d_in[3];
    const float* bq = (const float*)d_in[4];
    const float* Wk = (const float*)d_in[5];
    const float* bk = (const float*)d_in[6];
    const float* Wv = (const float*)d_in[7];
    const float* bv = (const float*)d_in[8];
    const float* Wo = (const float*)d_in[9];
    const float* bo = (const float*)d_in[10];

    char* ws = (char*)d_ws;
    const size_t MB = 1ull << 20;
    const dim3 twg(16, 16), blk(256);

    if (ws_size >= 64 * MB) {
        // fused path
        bf16* Wtq = (bf16*)(ws + 0 * MB);
        bf16* Wtk = (bf16*)(ws + 2 * MB);
        bf16* Wtv = (bf16*)(ws + 4 * MB);
        bf16* Wto = (bf16*)(ws + 6 * MB);
        bf16* qc  = (bf16*)(ws + 8 * MB);
        bf16* kc  = (bf16*)(ws + 16 * MB);
        bf16* vc  = (bf16*)(ws + 24 * MB);
        bf16* Qb  = (bf16*)(ws + 32 * MB);
        bf16* Kb  = (bf16*)(ws + 40 * MB);
        bf16* Vtb = (bf16*)(ws + 48 * MB);
        bf16* AOb = kc;  // kc free after QKV gemm

        k_transpose_w<<<twg, blk, 0, stream>>>(Wq, Wtq, QSCL);
        k_transpose_w<<<twg, blk, 0, stream>>>(Wk, Wtk, 1.0f);
        k_transpose_w<<<twg, blk, 0, stream>>>(Wv, Wtv, 1.0f);
        k_transpose_w<<<twg, blk, 0, stream>>>(Wo, Wto, 1.0f);
        k_cvt3<<<12288, blk, 0, stream>>>(q, k, v, qc, kc, vc);
        k_gemm_qkv<<<768, blk, 0, stream>>>(qc, kc, vc, Wtq, Wtk, Wtv, bq, bk, bv, Qb, Kb, Vtb);
        k_attn<<<256, 512, 0, stream>>>(Qb, Kb, Vtb, AOb);
        k_gemm_out<<<512, blk, 0, stream>>>(AOb, Wto, bo, (float*)d_out);
    } else {
        // sequential fallback (34 MB ws; cvt scratch lives in d_out until final gemm)
        bf16* Wt   = (bf16*)(ws + 0 * MB);
        bf16* Qb   = (bf16*)(ws + 2 * MB);
        bf16* Kb   = (bf16*)(ws + 10 * MB);
        bf16* Vtb  = (bf16*)(ws + 18 * MB);
        bf16* AOb  = (bf16*)(ws + 26 * MB);
        bf16* Cb   = (bf16*)d_out;     // 8 MB bf16 scratch inside the 16.78 MB output

        k_cvt1<<<4096, blk, 0, stream>>>(q, Cb);
        k_transpose_w<<<twg, blk, 0, stream>>>(Wq, Wt, QSCL);
        k_gemm_proj<<<256, blk, 0, stream>>>(Cb, Wt, bq, QSCL, (void*)Qb);
        k_cvt1<<<4096, blk, 0, stream>>>(k, Cb);
        k_transpose_w<<<twg, blk, 0, stream>>>(Wk, Wt, 1.0f);
        k_gemm_proj<<<256, blk, 0, stream>>>(Cb, Wt, bk, 1.0f, (void*)Kb);
        k_cvt1<<<4096, blk, 0, stream>>>(v, Cb);
        k_transpose_w<<<twg, blk, 0, stream>>>(Wv, Wt, 1.0f);
        k_gemm_vt<<<256, blk, 0, stream>>>(Wt, Cb, bv, Vtb);
        k_transpose_w<<<twg, blk, 0, stream>>>(Wo, Wt, 1.0f);
        k_attn<<<256, 512, 0, stream>>>(Qb, Kb, Vtb, AOb);
        k_gemm_out<<<512, blk, 0, stream>>>(AOb, Wt, bo, (float*)d_out);
    }
}

// Round 10
// 142.534 us; speedup vs baseline: 1.1351x; 1.0119x over previous
//
#include <hip/hip_runtime.h>
#include <hip/hip_bf16.h>
#include <stdint.h>

typedef __bf16 bf16;
typedef __bf16 bf16x8 __attribute__((ext_vector_type(8)));
typedef __bf16 bf16x4 __attribute__((ext_vector_type(4)));
typedef float  f32x4  __attribute__((ext_vector_type(4)));
typedef float  f32x16 __attribute__((ext_vector_type(16)));
typedef uint32_t u32;

#define MFMA16(a,b,c) __builtin_amdgcn_mfma_f32_16x16x32_bf16((a),(b),(c),0,0,0)
#define MFMA32(a,b,c) __builtin_amdgcn_mfma_f32_32x32x16_bf16((a),(b),(c),0,0,0)

// 0.125 (1/sqrt(64)) * log2(e): folded into Wq/bq so softmax runs in exp2 domain.
#define QSCL 0.1803368801111204f

// ---------- helpers ----------
__device__ __forceinline__ u32 sx32(u32 x) {  // value from lane^32 (HW-verified r3)
    return (u32)__shfl_xor((int)x, 32, 64);
}
__device__ __forceinline__ float swapred_max(float v) {
    return fmaxf(v, __builtin_bit_cast(float, sx32(__builtin_bit_cast(u32, v))));
}
__device__ __forceinline__ float swapred_sum(float v) {
    return v + __builtin_bit_cast(float, sx32(__builtin_bit_cast(u32, v)));
}
__device__ __forceinline__ u32 pkbf(float lo, float hi) {
    union { bf16 h[2]; u32 u; } un;
    un.h[0] = (bf16)lo; un.h[1] = (bf16)hi;
    return un.u;
}
// p[16] = exp'd scores for one 32-row K-block; lane (lm,hi) holds k_local(r) =
// (r&3) + 8*(r>>2) + 4*hi for col q=lm. Produce PV B-frags f0 (k=0..15) and
// f1 (k=16..31): lane needs k = 16*ks + hi*8 + j (j=0..7) at col q=lm.
__device__ __forceinline__ void pack_frags(const float* p, int hi, bf16x8& f0, bf16x8& f1) {
    u32 k01 = pkbf(p[0],  p[1]),  k23 = pkbf(p[2],  p[3]);
    u32 k45 = pkbf(p[4],  p[5]),  k67 = pkbf(p[6],  p[7]);
    u32 k89 = pkbf(p[8],  p[9]),  kab = pkbf(p[10], p[11]);
    u32 kcd = pkbf(p[12], p[13]), kef = pkbf(p[14], p[15]);
    u32 x01 = sx32(k01), x23 = sx32(k23), x45 = sx32(k45), x67 = sx32(k67);
    u32 x89 = sx32(k89), xab = sx32(kab), xcd = sx32(kcd), xef = sx32(kef);
    union { u32 w[4]; bf16x8 v; } u0, u1;
    u0.w[0] = hi ? x45 : k01;  u0.w[1] = hi ? x67 : k23;
    u0.w[2] = hi ? k45 : x01;  u0.w[3] = hi ? k67 : x23;
    u1.w[0] = hi ? xcd : k89;  u1.w[1] = hi ? xef : kab;
    u1.w[2] = hi ? kcd : x89;  u1.w[3] = hi ? kef : xab;
    f0 = u0.v; f1 = u1.v;
}

// ---------------- fp32 -> bf16 converts ----------------
__global__ __launch_bounds__(256) void k_cvt3(const float* __restrict__ a, const float* __restrict__ b,
                                              const float* __restrict__ c,
                                              bf16* __restrict__ x, bf16* __restrict__ y,
                                              bf16* __restrict__ z) {
    int i = blockIdx.x * 256 + threadIdx.x;          // vec4 index, 3 * 2^20 total
    int t = i >> 20;
    int r = (i & 1048575) << 2;
    const float* s = (t == 0) ? a : ((t == 1) ? b : c);
    bf16* d = (t == 0) ? x : ((t == 1) ? y : z);
    float4 v = *(const float4*)&s[r];
    bf16x4 w = {(bf16)v.x, (bf16)v.y, (bf16)v.z, (bf16)v.w};
    *(bf16x4*)&d[r] = w;
}
__global__ __launch_bounds__(256) void k_cvt1(const float* __restrict__ s, bf16* __restrict__ d) {
    int r = (blockIdx.x * 256 + threadIdx.x) << 2;
    float4 v = *(const float4*)&s[r];
    bf16x4 w = {(bf16)v.x, (bf16)v.y, (bf16)v.z, (bf16)v.w};
    *(bf16x4*)&d[r] = w;
}

// ---------------- weight transpose: W[k][n] fp32 -> Wt[n][k] bf16 (* scale) ----------------
__device__ __forceinline__ void transpose_body(const float* __restrict__ W, bf16* __restrict__ Wt,
                                               float scale, int n0, int k0) {
    __shared__ bf16 t[64][65];
    for (int i = 0; i < 16; ++i) {
        int idx = threadIdx.x + i * 256, r = idx >> 6, c = idx & 63;
        t[r][c] = (bf16)(W[(size_t)(k0 + r) * 1024 + n0 + c] * scale);
    }
    __syncthreads();
    for (int i = 0; i < 16; ++i) {
        int idx = threadIdx.x + i * 256, r = idx >> 6, c = idx & 63;
        Wt[(size_t)(n0 + r) * 1024 + k0 + c] = t[c][r];
    }
}
__global__ __launch_bounds__(256) void k_transpose_w(const float* __restrict__ W,
                                                     bf16* __restrict__ Wt, float scale) {
    transpose_body(W, Wt, scale, blockIdx.x * 64, blockIdx.y * 64);
}
// all four weights in one launch (grid 16x16x4)
__global__ __launch_bounds__(256) void k_transpose_w4(const float* __restrict__ Wq, const float* __restrict__ Wk,
                                                      const float* __restrict__ Wv, const float* __restrict__ Wo,
                                                      bf16* __restrict__ Wtq, bf16* __restrict__ Wtk,
                                                      bf16* __restrict__ Wtv, bf16* __restrict__ Wto) {
    int z = blockIdx.z;
    const float* W = (z == 0) ? Wq : (z == 1) ? Wk : (z == 2) ? Wv : Wo;
    bf16* Wt = (z == 0) ? Wtq : (z == 1) ? Wtk : (z == 2) ? Wtv : Wto;
    transpose_body(W, Wt, (z == 0) ? QSCL : 1.0f, blockIdx.x * 64, blockIdx.y * 64);
}

// ---------------- GEMM tile body (m97 pattern), 128x128, K=1024 ----------------
// out_mode 0: bf16 head layout [b][h][s][d] (proj Q/K; A=activation, Bt=weight)
// out_mode 2: bf16 Vt layout [bh][d][s]     (A=weight rows=h*64+d, Bt=activation rows=s)
__device__ __forceinline__ void gemm_tile(const bf16* __restrict__ A, const bf16* __restrict__ Bt,
                                          const float* __restrict__ bias, float bscale,
                                          void* __restrict__ Cp, int out_mode, int m0, int n0,
                                          bf16 (*As)[64], bf16 (*Bs)[64]) {
    const int tid = threadIdx.x;
    const int wid = tid >> 6, lane = tid & 63, lg = lane >> 4, lm = lane & 15;
    const int wr = wid >> 1, wc = wid & 1;
    const int grow = tid >> 3, gcol = (tid & 7) << 3;

    f32x4 acc[4][4] = {};

    for (int kt = 0; kt < 16; ++kt) {
        const int k0 = kt << 6;
        __syncthreads();
#pragma unroll
        for (int p = 0; p < 4; ++p) {
            __builtin_amdgcn_global_load_lds(
                (const __attribute__((address_space(1))) void*)(A + (size_t)(m0 + p * 32 + grow) * 1024 + k0 + gcol),
                (__attribute__((address_space(3))) void*)(&As[p * 32 + wid * 8][0]), 16, 0, 0);
            __builtin_amdgcn_global_load_lds(
                (const __attribute__((address_space(1))) void*)(Bt + (size_t)(n0 + p * 32 + grow) * 1024 + k0 + gcol),
                (__attribute__((address_space(3))) void*)(&Bs[p * 32 + wid * 8][0]), 16, 0, 0);
        }
        __syncthreads();
#pragma unroll
        for (int kk = 0; kk < 2; ++kk) {
            bf16x8 a[4], b[4];
#pragma unroll
            for (int i = 0; i < 4; ++i) a[i] = *(const bf16x8*)&As[wr * 64 + i * 16 + lm][kk * 32 + lg * 8];
#pragma unroll
            for (int j = 0; j < 4; ++j) b[j] = *(const bf16x8*)&Bs[wc * 64 + j * 16 + lm][kk * 32 + lg * 8];
#pragma unroll
            for (int i = 0; i < 4; ++i)
#pragma unroll
                for (int j = 0; j < 4; ++j) acc[i][j] = MFMA16(a[i], b[j], acc[i][j]);
        }
    }

    for (int i = 0; i < 4; ++i) {
        for (int j = 0; j < 4; ++j) {
            int col = n0 + wc * 64 + j * 16 + lm;
            for (int q = 0; q < 4; ++q) {
                int row = m0 + wr * 64 + i * 16 + lg * 4 + q;
                if (out_mode == 0) {  // bf16 head layout [b][h][s][d]
                    float val = acc[i][j][q] + bscale * bias[col];
                    int bb = row >> 11, s = row & 2047, h = col >> 6, d = col & 63;
                    ((bf16*)Cp)[(((size_t)bb * 16 + h) * 2048 + s) * 64 + d] = (bf16)val;
                } else {              // Vt layout [bh][d][s], bias per ROW
                    float val = acc[i][j][q] + bias[row];
                    size_t idx = (((size_t)(col >> 11) * 16 + (row >> 6)) * 64 + (row & 63)) * 2048 + (col & 2047);
                    ((bf16*)Cp)[idx] = (bf16)val;
                }
            }
        }
    }
}

// XCD-stripe decode for M=4096,N=1024: xcd owns m-tiles 4*xcd..4*xcd+3.
__device__ __forceinline__ void tile_decode(int r, int& m0, int& n0) {
    int xcd = r & 7, slot = (r >> 3) & 3, n = (r >> 5) & 7;
    m0 = (xcd * 4 + slot) * 128;
    n0 = n * 128;
}
// decode for Vt gemm (M=1024 weight-rows, N=4096 seq): xcd owns 4 n-tiles.
__device__ __forceinline__ void tile_decode_vt(int r, int& m0, int& n0) {
    int xcd = r & 7, loc = r >> 3;       // loc in [0,32)
    int nslot = loc & 3, m = loc >> 2;   // m in [0,8)
    n0 = (xcd * 4 + nslot) * 128;
    m0 = m * 128;
}

__global__ __launch_bounds__(256, 4) void k_gemm_proj(const bf16* __restrict__ A,
                                                      const bf16* __restrict__ Bt,
                                                      const float* __restrict__ bias, float bscale,
                                                      void* __restrict__ Cp) {
    __shared__ bf16 As[128][64];
    __shared__ bf16 Bs[128][64];
    int m0, n0;
    tile_decode(blockIdx.x, m0, n0);
    gemm_tile(A, Bt, bias, bscale, Cp, 0, m0, n0, As, Bs);
}

__global__ __launch_bounds__(256, 4) void k_gemm_vt(const bf16* __restrict__ Wtv,
                                                    const bf16* __restrict__ vc,
                                                    const float* __restrict__ bias,
                                                    bf16* __restrict__ Vtb) {
    __shared__ bf16 As[128][64];
    __shared__ bf16 Bs[128][64];
    int m0, n0;
    tile_decode_vt(blockIdx.x, m0, n0);
    gemm_tile(Wtv, vc, bias, 1.0f, (void*)Vtb, 2, m0, n0, As, Bs);
}

// fused Q/K/V projections: grid 768, z selects matrix (3 blocks/CU co-resident)
__global__ __launch_bounds__(256, 4) void k_gemm_qkv(const bf16* __restrict__ qc, const bf16* __restrict__ kc,
                                                     const bf16* __restrict__ vc,
                                                     const bf16* __restrict__ Wtq, const bf16* __restrict__ Wtk,
                                                     const bf16* __restrict__ Wtv,
                                                     const float* __restrict__ bq, const float* __restrict__ bk,
                                                     const float* __restrict__ bv,
                                                     bf16* __restrict__ Qb, bf16* __restrict__ Kb,
                                                     bf16* __restrict__ Vtb) {
    __shared__ bf16 As[128][64];
    __shared__ bf16 Bs[128][64];
    int l = blockIdx.x, z = l >> 8, r = l & 255;
    int m0, n0;
    if (z == 2) {
        tile_decode_vt(r, m0, n0);
        gemm_tile(Wtv, vc, bv, 1.0f, (void*)Vtb, 2, m0, n0, As, Bs);
    } else {
        tile_decode(r, m0, n0);
        const bf16* A  = (z == 0) ? qc : kc;
        const bf16* Bt = (z == 0) ? Wtq : Wtk;
        const float* bias = (z == 0) ? bq : bk;
        float bscale = (z == 0) ? QSCL : 1.0f;
        bf16* Cp = (z == 0) ? Qb : Kb;
        gemm_tile(A, Bt, bias, bscale, (void*)Cp, 0, m0, n0, As, Bs);
    }
}

// ---------------- output projection: 128x64 tiles, 512 blocks (2/CU) ----------------
__global__ __launch_bounds__(256, 4) void k_gemm_out(const bf16* __restrict__ A,
                                                     const bf16* __restrict__ Bt,
                                                     const float* __restrict__ bias,
                                                     float* __restrict__ C) {
    __shared__ bf16 As[128][64];
    __shared__ bf16 Bs[64][64];
    const int tid = threadIdx.x;
    const int wid = tid >> 6, lane = tid & 63, lg = lane >> 4, lm = lane & 15;
    const int grow = tid >> 3, gcol = (tid & 7) << 3;
    const int r = blockIdx.x;
    const int xcd = r & 7, loc = r >> 3;
    const int mslot = loc & 3, n = loc >> 2;
    const int m0 = (xcd * 4 + mslot) * 128, n0 = n * 64;

    f32x4 acc[2][4] = {};

    for (int kt = 0; kt < 16; ++kt) {
        const int k0 = kt << 6;
        __syncthreads();
#pragma unroll
        for (int p = 0; p < 4; ++p)
            __builtin_amdgcn_global_load_lds(
                (const __attribute__((address_space(1))) void*)(A + (size_t)(m0 + p * 32 + grow) * 1024 + k0 + gcol),
                (__attribute__((address_space(3))) void*)(&As[p * 32 + wid * 8][0]), 16, 0, 0);
#pragma unroll
        for (int p = 0; p < 2; ++p)
            __builtin_amdgcn_global_load_lds(
                (const __attribute__((address_space(1))) void*)(Bt + (size_t)(n0 + p * 32 + grow) * 1024 + k0 + gcol),
                (__attribute__((address_space(3))) void*)(&Bs[p * 32 + wid * 8][0]), 16, 0, 0);
        __syncthreads();
#pragma unroll
        for (int kk = 0; kk < 2; ++kk) {
            bf16x8 a[2], b[4];
#pragma unroll
            for (int i = 0; i < 2; ++i) a[i] = *(const bf16x8*)&As[wid * 32 + i * 16 + lm][kk * 32 + lg * 8];
#pragma unroll
            for (int j = 0; j < 4; ++j) b[j] = *(const bf16x8*)&Bs[j * 16 + lm][kk * 32 + lg * 8];
#pragma unroll
            for (int i = 0; i < 2; ++i)
#pragma unroll
                for (int j = 0; j < 4; ++j) acc[i][j] = MFMA16(a[i], b[j], acc[i][j]);
        }
    }

    for (int i = 0; i < 2; ++i) {
        for (int j = 0; j < 4; ++j) {
            int col = n0 + j * 16 + lm;
            float bv = bias[col];
            for (int q = 0; q < 4; ++q) {
                int row = m0 + wid * 32 + i * 16 + lg * 4 + q;
                C[(size_t)row * 1024 + col] = acc[i][j][q] + bv;
            }
        }
    }
}

// ---------------- flash attention: 8 waves x 64 q-rows, KVBLK=32, split-KV(2) ----------------
// Each wave owns TWO independent 32-q-row sets (A/B) -> K/V LDS reads amortized over 2x q
// (8 ds_read_b128 per 64q*32k vs 16 per 32q*64k) and softmax chains A/B give intra-wave ILP.
// K tile: LDS [32 keys][128B]; V tile: LDS [32 rows][128B] where row r = d-rows {r, r+32};
// both with the proven (row&7) chunk-XOR swizzle via pre-swizzled glds SOURCE.
// Grid = 32 bh x 4 qt x 2 sp = 256. Writes unnormalized partials + (m,l); k_combine merges.
__global__ __launch_bounds__(512, 2) void k_attn(const bf16* __restrict__ Q,
                                                 const bf16* __restrict__ Kb,
                                                 const bf16* __restrict__ Vt,
                                                 bf16* __restrict__ Opart,
                                                 float* __restrict__ ml) {
    __shared__ bf16 Ks[2][32 * 64];
    __shared__ bf16 Vs[2][32 * 64];
    const int tid = threadIdx.x;
    const int wid = tid >> 6, lane = tid & 63;
    const int lm = lane & 31, hi = lane >> 5;
    const int bid = blockIdx.x;
    const int bh = bid & 31, qt = (bid >> 5) & 3, sp = bid >> 7;  // bid%8==bh%8: XCD locality
    const size_t qk_base = (size_t)bh * (2048 * 64);
    const size_t vt_base = (size_t)bh * (64 * 2048);
    const int kt0 = sp * 32, kt1 = kt0 + 32;        // 32-key tiles
    const int qrowA = qt * 512 + wid * 64 + lm;
    const int qrowB = qrowA + 32;

    // staging: threads 0..255 stage K (4KB), 256..511 stage V (4KB); one glds each.
    // LDS[row][pc] holds logical chunk lc = pc ^ (row&7)  (source pre-swizzled).
    const int u = tid & 255;
    const int srow = u >> 3, pc = u & 7;
    const int lc = pc ^ (srow & 7);
    const bf16* kst = Kb + qk_base + (size_t)srow * 64 + lc * 8;                           // + kt*2048
    const bf16* vst = Vt + vt_base + (size_t)(srow + ((lc >> 2) << 5)) * 2048 + (lc & 3) * 8;  // + kt*32
    const int sbase = (wid & 3) * 1024;             // dest byte base within buffer

#define STAGE(T, BUF)                                                                             \
    do {                                                                                          \
        if (tid < 256)                                                                            \
            __builtin_amdgcn_global_load_lds(                                                     \
                (const __attribute__((address_space(1))) void*)(kst + (size_t)(T) * 2048),        \
                (__attribute__((address_space(3))) void*)((char*)&Ks[BUF][0] + sbase), 16, 0, 0); \
        else                                                                                      \
            __builtin_amdgcn_global_load_lds(                                                     \
                (const __attribute__((address_space(1))) void*)(vst + (size_t)(T) * 32),          \
                (__attribute__((address_space(3))) void*)((char*)&Vs[BUF][0] + sbase), 16, 0, 0); \
    } while (0)

    // Q fragments for both sets
    bf16x8 qfA[4], qfB[4];
    {
        const bf16* qpA = Q + qk_base + (size_t)qrowA * 64 + hi * 8;
        const bf16* qpB = qpA + 32 * 64;
#pragma unroll
        for (int f = 0; f < 4; ++f) {
            qfA[f] = *(const bf16x8*)(qpA + f * 16);
            qfB[f] = *(const bf16x8*)(qpB + f * 16);
        }
    }

    f32x16 O0A = {}, O1A = {}, O0B = {}, O1B = {};
    float mA = -1e30f, mB = -1e30f, lsA = 0.f, lsB = 0.f;
    const int swz = lm & 7;

    STAGE(kt0, 0);
    __syncthreads();

    int cur = 0;
#pragma unroll 1
    for (int kt = kt0; kt < kt1; ++kt) {
        if (kt + 1 < kt1) STAGE(kt + 1, cur ^ 1);

        const char* Ksc = (const char*)&Ks[cur][0];
        const char* Vsc = (const char*)&Vs[cur][0];

        // K frags: key row = lm, d-chunk = (f<<1)|hi  (shared by both q-sets)
        bf16x8 kf[4];
#pragma unroll
        for (int f = 0; f < 4; ++f)
            kf[f] = *(const bf16x8*)(Ksc + lm * 128 + (((((f << 1) | hi)) ^ swz) << 4));

        // S^T = K · Q^T for both sets (independent chains)
        f32x16 sA = {}, sB = {};
#pragma unroll
        for (int f = 0; f < 4; ++f) sA = MFMA32(kf[f], qfA[f], sA);
#pragma unroll
        for (int f = 0; f < 4; ++f) sB = MFMA32(kf[f], qfB[f], sB);

        // row-max per set
        float tA[8], tB[8];
#pragma unroll
        for (int r = 0; r < 8; ++r) { tA[r] = fmaxf(sA[r], sA[r + 8]); tB[r] = fmaxf(sB[r], sB[r + 8]); }
#pragma unroll
        for (int st = 4; st; st >>= 1)
#pragma unroll
            for (int r = 0; r < st; ++r) { tA[r] = fmaxf(tA[r], tA[r + st]); tB[r] = fmaxf(tB[r], tB[r + st]); }
        float pmA = swapred_max(tA[0]);
        float pmB = swapred_max(tB[0]);

        // defer-max per set (exp2 domain, THR=8)
        if (!__all(pmA <= mA + 8.0f)) {
            float mn = fmaxf(mA, pmA);
            float c = __builtin_amdgcn_exp2f(mA - mn);
            lsA *= c; O0A *= c; O1A *= c; mA = mn;
        }
        if (!__all(pmB <= mB + 8.0f)) {
            float mn = fmaxf(mB, pmB);
            float c = __builtin_amdgcn_exp2f(mB - mn);
            lsB *= c; O0B *= c; O1B *= c; mB = mn;
        }

        // P = exp2(S - m), lane-local row-sums (cross-half swap deferred to epilogue)
        float peA[16], peB[16];
#pragma unroll
        for (int r = 0; r < 16; ++r) peA[r] = __builtin_amdgcn_exp2f(sA[r] - mA);
#pragma unroll
        for (int r = 0; r < 16; ++r) peB[r] = __builtin_amdgcn_exp2f(sB[r] - mB);
        float uA[8], uB[8];
#pragma unroll
        for (int r = 0; r < 8; ++r) { uA[r] = peA[r] + peA[r + 8]; uB[r] = peB[r] + peB[r + 8]; }
#pragma unroll
        for (int st = 4; st; st >>= 1)
#pragma unroll
            for (int r = 0; r < st; ++r) { uA[r] += uA[r + st]; uB[r] += uB[r + st]; }
        lsA += uA[0];
        lsB += uB[0];

        // P -> PV B-frags
        bf16x8 pfA[2], pfB[2];
        pack_frags(peA, hi, pfA[0], pfA[1]);
        pack_frags(peB, hi, pfB[0], pfB[1]);

        // V frags: LDS row lm = d-rows {lm, lm+32}; logical chunk = (dh<<2)|(ks<<1)|hi
        bf16x8 vf[2][2];
#pragma unroll
        for (int dh = 0; dh < 2; ++dh)
#pragma unroll
            for (int ks = 0; ks < 2; ++ks)
                vf[dh][ks] = *(const bf16x8*)(Vsc + lm * 128 + ((((dh << 2) | (ks << 1) | hi) ^ swz) << 4));

        // O^T += Vt · P^T (4 independent accumulators)
        O0A = MFMA32(vf[0][0], pfA[0], O0A);
        O0A = MFMA32(vf[0][1], pfA[1], O0A);
        O1A = MFMA32(vf[1][0], pfA[0], O1A);
        O1A = MFMA32(vf[1][1], pfA[1], O1A);
        O0B = MFMA32(vf[0][0], pfB[0], O0B);
        O0B = MFMA32(vf[0][1], pfB[1], O0B);
        O1B = MFMA32(vf[1][0], pfB[0], O1B);
        O1B = MFMA32(vf[1][1], pfB[1], O1B);

        __syncthreads();
        cur ^= 1;
    }
#undef STAGE

    // unnormalized partials + (m,l) for both sets
    float lrA = swapred_sum(lsA);
    float lrB = swapred_sum(lsB);
    const size_t r2A = ((size_t)bh * 2048 + qrowA) * 2 + sp;
    const size_t r2B = r2A + 64;   // qrowB = qrowA+32 -> +64 in r2 units
    bf16* opA = Opart + r2A * 64 + 4 * hi;
    bf16* opB = Opart + r2B * 64 + 4 * hi;
#pragma unroll
    for (int t = 0; t < 4; ++t) {
        bf16x4 a0, a1, b0, b1;
#pragma unroll
        for (int e = 0; e < 4; ++e) {
            a0[e] = (bf16)O0A[4 * t + e];
            a1[e] = (bf16)O1A[4 * t + e];
            b0[e] = (bf16)O0B[4 * t + e];
            b1[e] = (bf16)O1B[4 * t + e];
        }
        *(bf16x4*)(opA + 8 * t)      = a0;
        *(bf16x4*)(opA + 32 + 8 * t) = a1;
        *(bf16x4*)(opB + 8 * t)      = b0;
        *(bf16x4*)(opB + 32 + 8 * t) = b1;
    }
    if (hi == 0) {
        float2 vA = {mA, lrA};
        float2 vB = {mB, lrB};
        ((float2*)ml)[r2A] = vA;
        ((float2*)ml)[r2B] = vB;
    }
}

// ---------------- combine: merge 2 split partials -> AOb [b][s][h*64+d] bf16 ----------------
__global__ __launch_bounds__(256) void k_combine(const bf16* __restrict__ Opart,
                                                 const float* __restrict__ ml,
                                                 bf16* __restrict__ AOb) {
    int e8 = blockIdx.x * 256 + threadIdx.x;   // 524288 total
    int row = e8 >> 3, dc = (e8 & 7) << 3;
    float2 ml0 = ((const float2*)ml)[row * 2 + 0];
    float2 ml1 = ((const float2*)ml)[row * 2 + 1];
    float M  = fmaxf(ml0.x, ml1.x);
    float w0 = __builtin_amdgcn_exp2f(ml0.x - M);
    float w1 = __builtin_amdgcn_exp2f(ml1.x - M);
    float L  = w0 * ml0.y + w1 * ml1.y;
    float a0 = w0 / L, a1 = w1 / L;
    bf16x8 p0 = *(const bf16x8*)&Opart[((size_t)row * 2 + 0) * 64 + dc];
    bf16x8 p1 = *(const bf16x8*)&Opart[((size_t)row * 2 + 1) * 64 + dc];
    bf16x8 o;
#pragma unroll
    for (int j = 0; j < 8; ++j) o[j] = (bf16)(a0 * (float)p0[j] + a1 * (float)p1[j]);
    int bh = row >> 11, qrow = row & 2047;
    int bb = bh >> 4, h = bh & 15;
    *(bf16x8*)&AOb[((size_t)bb * 2048 + qrow) * 1024 + h * 64 + dc] = o;
}

extern "C" void kernel_launch(void* const* d_in, const int* in_sizes, int n_in,
                              void* d_out, int out_size, void* d_ws, size_t ws_size,
                              hipStream_t stream) {
    const float* q  = (const float*)d_in[0];
    const float* k  = (const float*)d_in[1];
    const float* v  = (const float*)d_in[2];
    const float* Wq = (const float*)d_in[3];
    const float* bq = (const float*)d_in[4];
    const float* Wk = (const float*)d_in[5];
    const float* bk = (const float*)d_in[6];
    const float* Wv = (const float*)d_in[7];
    const float* bv = (const float*)d_in[8];
    const float* Wo = (const float*)d_in[9];
    const float* bo = (const float*)d_in[10];

    char* ws = (char*)d_ws;
    const size_t MB = 1ull << 20;
    const dim3 twg(16, 16), blk(256);
    bf16* Opart = (bf16*)d_out;   // 16.78 MB scratch until the final GEMM (exact fit)

    if (ws_size >= 64 * MB) {
        // fused path
        bf16* Wtq = (bf16*)(ws + 0 * MB);
        bf16* Wtk = (bf16*)(ws + 2 * MB);
        bf16* Wtv = (bf16*)(ws + 4 * MB);
        bf16* Wto = (bf16*)(ws + 6 * MB);
        bf16* qc  = (bf16*)(ws + 8 * MB);
        bf16* kc  = (bf16*)(ws + 16 * MB);
        bf16* vc  = (bf16*)(ws + 24 * MB);
        bf16* Qb  = (bf16*)(ws + 32 * MB);
        bf16* Kb  = (bf16*)(ws + 40 * MB);
        bf16* Vtb = (bf16*)(ws + 48 * MB);
        float* mlb = (float*)qc;  // qc free after QKV gemm
        bf16* AOb  = kc;          // kc free after QKV gemm

        k_transpose_w4<<<dim3(16, 16, 4), blk, 0, stream>>>(Wq, Wk, Wv, Wo, Wtq, Wtk, Wtv, Wto);
        k_cvt3<<<12288, blk, 0, stream>>>(q, k, v, qc, kc, vc);
        k_gemm_qkv<<<768, blk, 0, stream>>>(qc, kc, vc, Wtq, Wtk, Wtv, bq, bk, bv, Qb, Kb, Vtb);
        k_attn<<<256, 512, 0, stream>>>(Qb, Kb, Vtb, Opart, mlb);
        k_combine<<<2048, blk, 0, stream>>>(Opart, mlb, AOb);
        k_gemm_out<<<512, blk, 0, stream>>>(AOb, Wto, bo, (float*)d_out);
    } else {
        // sequential fallback (27 MB ws; bf16 cvt scratch lives inside d_out pre-attn)
        bf16* Wt   = (bf16*)(ws + 0 * MB);
        bf16* Qb   = (bf16*)(ws + 2 * MB);
        bf16* Kb   = (bf16*)(ws + 10 * MB);
        bf16* Vtb  = (bf16*)(ws + 18 * MB);
        float* mlb = (float*)(ws + 26 * MB);
        bf16* Cb   = (bf16*)d_out;     // 8 MB bf16 scratch, dead before attn writes Opart
        bf16* AOb  = Qb;               // Qb dead after attn

        k_cvt1<<<4096, blk, 0, stream>>>(q, Cb);
        k_transpose_w<<<twg, blk, 0, stream>>>(Wq, Wt, QSCL);
        k_gemm_proj<<<256, blk, 0, stream>>>(Cb, Wt, bq, QSCL, (void*)Qb);
        k_cvt1<<<4096, blk, 0, stream>>>(k, Cb);
        k_transpose_w<<<twg, blk, 0, stream>>>(Wk, Wt, 1.0f);
        k_gemm_proj<<<256, blk, 0, stream>>>(Cb, Wt, bk, 1.0f, (void*)Kb);
        k_cvt1<<<4096, blk, 0, stream>>>(v, Cb);
        k_transpose_w<<<twg, blk, 0, stream>>>(Wv, Wt, 1.0f);
        k_gemm_vt<<<256, blk, 0, stream>>>(Wt, Cb, bv, Vtb);
        k_transpose_w<<<twg, blk, 0, stream>>>(Wo, Wt, 1.0f);
        k_attn<<<256, 512, 0, stream>>>(Qb, Kb, Vtb, Opart, mlb);
        k_combine<<<2048, blk, 0, stream>>>(Opart, mlb, AOb);
        k_gemm_out<<<512, blk, 0, stream>>>(AOb, Wt, bo, (float*)d_out);
    }
}

// Round 11
// 136.750 us; speedup vs baseline: 1.1832x; 1.0423x over previous
//
#include <hip/hip_runtime.h>
#include <hip/hip_bf16.h>
#include <stdint.h>

typedef __bf16 bf16;
typedef __bf16 bf16x8 __attribute__((ext_vector_type(8)));
typedef __bf16 bf16x4 __attribute__((ext_vector_type(4)));
typedef float  f32x4  __attribute__((ext_vector_type(4)));
typedef float  f32x16 __attribute__((ext_vector_type(16)));
typedef uint32_t u32;

#define MFMA16(a,b,c) __builtin_amdgcn_mfma_f32_16x16x32_bf16((a),(b),(c),0,0,0)
#define MFMA32(a,b,c) __builtin_amdgcn_mfma_f32_32x32x16_bf16((a),(b),(c),0,0,0)

// 0.125 (1/sqrt(64)) * log2(e): folded into Wq/bq so softmax runs in exp2 domain.
#define QSCL 0.1803368801111204f

// ---------- helpers ----------
__device__ __forceinline__ u32 sx32(u32 x) {  // value from lane^32 (HW-verified r3)
    return (u32)__shfl_xor((int)x, 32, 64);
}
__device__ __forceinline__ float swapred_max(float v) {
    return fmaxf(v, __builtin_bit_cast(float, sx32(__builtin_bit_cast(u32, v))));
}
__device__ __forceinline__ float swapred_sum(float v) {
    return v + __builtin_bit_cast(float, sx32(__builtin_bit_cast(u32, v)));
}
__device__ __forceinline__ u32 pkbf(float lo, float hi) {
    union { bf16 h[2]; u32 u; } un;
    un.h[0] = (bf16)lo; un.h[1] = (bf16)hi;
    return un.u;
}
// p[16] = exp'd scores for one 32-row K-block; lane (lm,hi) holds k_local(r) =
// (r&3) + 8*(r>>2) + 4*hi for col q=lm. Produce PV B-frags f0 (k=0..15) and
// f1 (k=16..31): lane needs k = 16*ks + hi*8 + j (j=0..7) at col q=lm.
__device__ __forceinline__ void pack_frags(const float* p, int hi, bf16x8& f0, bf16x8& f1) {
    u32 k01 = pkbf(p[0],  p[1]),  k23 = pkbf(p[2],  p[3]);
    u32 k45 = pkbf(p[4],  p[5]),  k67 = pkbf(p[6],  p[7]);
    u32 k89 = pkbf(p[8],  p[9]),  kab = pkbf(p[10], p[11]);
    u32 kcd = pkbf(p[12], p[13]), kef = pkbf(p[14], p[15]);
    u32 x01 = sx32(k01), x23 = sx32(k23), x45 = sx32(k45), x67 = sx32(k67);
    u32 x89 = sx32(k89), xab = sx32(kab), xcd = sx32(kcd), xef = sx32(kef);
    union { u32 w[4]; bf16x8 v; } u0, u1;
    u0.w[0] = hi ? x45 : k01;  u0.w[1] = hi ? x67 : k23;
    u0.w[2] = hi ? k45 : x01;  u0.w[3] = hi ? k67 : x23;
    u1.w[0] = hi ? xcd : k89;  u1.w[1] = hi ? xef : kab;
    u1.w[2] = hi ? kcd : x89;  u1.w[3] = hi ? kef : xab;
    f0 = u0.v; f1 = u1.v;
}

// ---------------- weight transpose: W[k][n] fp32 -> Wt[n][k] bf16 (* scale) ----------------
__device__ __forceinline__ void transpose_body(const float* __restrict__ W, bf16* __restrict__ Wt,
                                               float scale, int n0, int k0) {
    __shared__ bf16 t[64][65];
    for (int i = 0; i < 16; ++i) {
        int idx = threadIdx.x + i * 256, r = idx >> 6, c = idx & 63;
        t[r][c] = (bf16)(W[(size_t)(k0 + r) * 1024 + n0 + c] * scale);
    }
    __syncthreads();
    for (int i = 0; i < 16; ++i) {
        int idx = threadIdx.x + i * 256, r = idx >> 6, c = idx & 63;
        Wt[(size_t)(n0 + r) * 1024 + k0 + c] = t[c][r];
    }
}
__global__ __launch_bounds__(256) void k_transpose_w(const float* __restrict__ W,
                                                     bf16* __restrict__ Wt, float scale) {
    transpose_body(W, Wt, scale, blockIdx.x * 64, blockIdx.y * 64);
}
// all four weights in one launch (grid 16x16x4)
__global__ __launch_bounds__(256) void k_transpose_w4(const float* __restrict__ Wq, const float* __restrict__ Wk,
                                                      const float* __restrict__ Wv, const float* __restrict__ Wo,
                                                      bf16* __restrict__ Wtq, bf16* __restrict__ Wtk,
                                                      bf16* __restrict__ Wtv, bf16* __restrict__ Wto) {
    int z = blockIdx.z;
    const float* W = (z == 0) ? Wq : (z == 1) ? Wk : (z == 2) ? Wv : Wo;
    bf16* Wt = (z == 0) ? Wtq : (z == 1) ? Wtk : (z == 2) ? Wtv : Wto;
    transpose_body(W, Wt, (z == 0) ? QSCL : 1.0f, blockIdx.x * 64, blockIdx.y * 64);
}

// ---------------- GEMM tile body (m97 pattern), 128x128, K=1024 ----------------
// A_F32 / B_F32: that operand is fp32 in global memory and is reg-staged with an
// on-the-fly bf16 convert (byte-identical LDS contents to the glds path; same RNE
// cast the old cvt pass used). bf16 operands use global_load_lds width-16.
// out_mode 0: bf16 head layout [b][h][s][d]; out_mode 2: bf16 Vt layout [bh][d][s].
template <int A_F32, int B_F32>
__device__ __forceinline__ void gemm_tile2(const void* __restrict__ Ap, const void* __restrict__ Btp,
                                           const float* __restrict__ bias, float bscale,
                                           void* __restrict__ Cp, int out_mode, int m0, int n0,
                                           bf16 (*As)[64], bf16 (*Bs)[64]) {
    const int tid = threadIdx.x;
    const int wid = tid >> 6, lane = tid & 63, lg = lane >> 4, lm = lane & 15;
    const int wr = wid >> 1, wc = wid & 1;
    const int grow = tid >> 3, gcol = (tid & 7) << 3;

    f32x4 acc[4][4] = {};

    for (int kt = 0; kt < 16; ++kt) {
        const int k0 = kt << 6;
        __syncthreads();
#pragma unroll
        for (int p = 0; p < 4; ++p) {
            const int r = p * 32 + grow;
            if constexpr (A_F32) {
                const float* A = (const float*)Ap;
                const float* src = A + (size_t)(m0 + r) * 1024 + k0 + gcol;
                float4 v0 = *(const float4*)src;
                float4 v1 = *(const float4*)(src + 4);
                bf16x8 w = {(bf16)v0.x, (bf16)v0.y, (bf16)v0.z, (bf16)v0.w,
                            (bf16)v1.x, (bf16)v1.y, (bf16)v1.z, (bf16)v1.w};
                *(bf16x8*)&As[r][gcol] = w;
            } else {
                const bf16* A = (const bf16*)Ap;
                __builtin_amdgcn_global_load_lds(
                    (const __attribute__((address_space(1))) void*)(A + (size_t)(m0 + r) * 1024 + k0 + gcol),
                    (__attribute__((address_space(3))) void*)(&As[p * 32 + wid * 8][0]), 16, 0, 0);
            }
            if constexpr (B_F32) {
                const float* B = (const float*)Btp;
                const float* src = B + (size_t)(n0 + r) * 1024 + k0 + gcol;
                float4 v0 = *(const float4*)src;
                float4 v1 = *(const float4*)(src + 4);
                bf16x8 w = {(bf16)v0.x, (bf16)v0.y, (bf16)v0.z, (bf16)v0.w,
                            (bf16)v1.x, (bf16)v1.y, (bf16)v1.z, (bf16)v1.w};
                *(bf16x8*)&Bs[r][gcol] = w;
            } else {
                const bf16* Bt = (const bf16*)Btp;
                __builtin_amdgcn_global_load_lds(
                    (const __attribute__((address_space(1))) void*)(Bt + (size_t)(n0 + r) * 1024 + k0 + gcol),
                    (__attribute__((address_space(3))) void*)(&Bs[p * 32 + wid * 8][0]), 16, 0, 0);
            }
        }
        __syncthreads();
#pragma unroll
        for (int kk = 0; kk < 2; ++kk) {
            bf16x8 a[4], b[4];
#pragma unroll
            for (int i = 0; i < 4; ++i) a[i] = *(const bf16x8*)&As[wr * 64 + i * 16 + lm][kk * 32 + lg * 8];
#pragma unroll
            for (int j = 0; j < 4; ++j) b[j] = *(const bf16x8*)&Bs[wc * 64 + j * 16 + lm][kk * 32 + lg * 8];
#pragma unroll
            for (int i = 0; i < 4; ++i)
#pragma unroll
                for (int j = 0; j < 4; ++j) acc[i][j] = MFMA16(a[i], b[j], acc[i][j]);
        }
    }

    for (int i = 0; i < 4; ++i) {
        for (int j = 0; j < 4; ++j) {
            int col = n0 + wc * 64 + j * 16 + lm;
            for (int q = 0; q < 4; ++q) {
                int row = m0 + wr * 64 + i * 16 + lg * 4 + q;
                if (out_mode == 0) {  // bf16 head layout [b][h][s][d]
                    float val = acc[i][j][q] + bscale * bias[col];
                    int bb = row >> 11, s = row & 2047, h = col >> 6, d = col & 63;
                    ((bf16*)Cp)[(((size_t)bb * 16 + h) * 2048 + s) * 64 + d] = (bf16)val;
                } else {              // Vt layout [bh][d][s], bias per ROW
                    float val = acc[i][j][q] + bias[row];
                    size_t idx = (((size_t)(col >> 11) * 16 + (row >> 6)) * 64 + (row & 63)) * 2048 + (col & 2047);
                    ((bf16*)Cp)[idx] = (bf16)val;
                }
            }
        }
    }
}

// XCD-stripe decode for M=4096,N=1024: xcd owns m-tiles 4*xcd..4*xcd+3.
__device__ __forceinline__ void tile_decode(int r, int& m0, int& n0) {
    int xcd = r & 7, slot = (r >> 3) & 3, n = (r >> 5) & 7;
    m0 = (xcd * 4 + slot) * 128;
    n0 = n * 128;
}
// decode for Vt gemm (M=1024 weight-rows, N=4096 seq): xcd owns 4 n-tiles.
__device__ __forceinline__ void tile_decode_vt(int r, int& m0, int& n0) {
    int xcd = r & 7, loc = r >> 3;       // loc in [0,32)
    int nslot = loc & 3, m = loc >> 2;   // m in [0,8)
    n0 = (xcd * 4 + nslot) * 128;
    m0 = m * 128;
}

// Q/K projection (A = fp32 activation, Bt = bf16 weight)
__global__ __launch_bounds__(256, 4) void k_gemm_proj(const float* __restrict__ A,
                                                      const bf16* __restrict__ Bt,
                                                      const float* __restrict__ bias, float bscale,
                                                      void* __restrict__ Cp) {
    __shared__ bf16 As[128][64];
    __shared__ bf16 Bs[128][64];
    int m0, n0;
    tile_decode(blockIdx.x, m0, n0);
    gemm_tile2<1, 0>((const void*)A, (const void*)Bt, bias, bscale, Cp, 0, m0, n0, As, Bs);
}

// V projection producing Vt directly (A = bf16 weight, Bt = fp32 activation)
__global__ __launch_bounds__(256, 4) void k_gemm_vt(const bf16* __restrict__ Wtv,
                                                    const float* __restrict__ v,
                                                    const float* __restrict__ bias,
                                                    bf16* __restrict__ Vtb) {
    __shared__ bf16 As[128][64];
    __shared__ bf16 Bs[128][64];
    int m0, n0;
    tile_decode_vt(blockIdx.x, m0, n0);
    gemm_tile2<0, 1>((const void*)Wtv, (const void*)v, bias, 1.0f, (void*)Vtb, 2, m0, n0, As, Bs);
}

// fused Q/K/V projections with in-staging fp32->bf16 cvt: grid 768 (3 blocks/CU)
__global__ __launch_bounds__(256, 4) void k_gemm_qkv(const float* __restrict__ q, const float* __restrict__ k,
                                                     const float* __restrict__ v,
                                                     const bf16* __restrict__ Wtq, const bf16* __restrict__ Wtk,
                                                     const bf16* __restrict__ Wtv,
                                                     const float* __restrict__ bq, const float* __restrict__ bk,
                                                     const float* __restrict__ bv,
                                                     bf16* __restrict__ Qb, bf16* __restrict__ Kb,
                                                     bf16* __restrict__ Vtb) {
    __shared__ bf16 As[128][64];
    __shared__ bf16 Bs[128][64];
    int l = blockIdx.x, z = l >> 8, r = l & 255;
    int m0, n0;
    if (z == 2) {
        tile_decode_vt(r, m0, n0);
        gemm_tile2<0, 1>((const void*)Wtv, (const void*)v, bv, 1.0f, (void*)Vtb, 2, m0, n0, As, Bs);
    } else {
        tile_decode(r, m0, n0);
        const float* A  = (z == 0) ? q : k;
        const bf16* Bt  = (z == 0) ? Wtq : Wtk;
        const float* bias = (z == 0) ? bq : bk;
        float bscale = (z == 0) ? QSCL : 1.0f;
        bf16* Cp = (z == 0) ? Qb : Kb;
        gemm_tile2<1, 0>((const void*)A, (const void*)Bt, bias, bscale, (void*)Cp, 0, m0, n0, As, Bs);
    }
}

// ---------------- output projection: 128x64 tiles, 512 blocks (2/CU) ----------------
__global__ __launch_bounds__(256, 4) void k_gemm_out(const bf16* __restrict__ A,
                                                     const bf16* __restrict__ Bt,
                                                     const float* __restrict__ bias,
                                                     float* __restrict__ C) {
    __shared__ bf16 As[128][64];
    __shared__ bf16 Bs[64][64];
    const int tid = threadIdx.x;
    const int wid = tid >> 6, lane = tid & 63, lg = lane >> 4, lm = lane & 15;
    const int grow = tid >> 3, gcol = (tid & 7) << 3;
    const int r = blockIdx.x;
    const int xcd = r & 7, loc = r >> 3;
    const int mslot = loc & 3, n = loc >> 2;
    const int m0 = (xcd * 4 + mslot) * 128, n0 = n * 64;

    f32x4 acc[2][4] = {};

    for (int kt = 0; kt < 16; ++kt) {
        const int k0 = kt << 6;
        __syncthreads();
#pragma unroll
        for (int p = 0; p < 4; ++p)
            __builtin_amdgcn_global_load_lds(
                (const __attribute__((address_space(1))) void*)(A + (size_t)(m0 + p * 32 + grow) * 1024 + k0 + gcol),
                (__attribute__((address_space(3))) void*)(&As[p * 32 + wid * 8][0]), 16, 0, 0);
#pragma unroll
        for (int p = 0; p < 2; ++p)
            __builtin_amdgcn_global_load_lds(
                (const __attribute__((address_space(1))) void*)(Bt + (size_t)(n0 + p * 32 + grow) * 1024 + k0 + gcol),
                (__attribute__((address_space(3))) void*)(&Bs[p * 32 + wid * 8][0]), 16, 0, 0);
        __syncthreads();
#pragma unroll
        for (int kk = 0; kk < 2; ++kk) {
            bf16x8 a[2], b[4];
#pragma unroll
            for (int i = 0; i < 2; ++i) a[i] = *(const bf16x8*)&As[wid * 32 + i * 16 + lm][kk * 32 + lg * 8];
#pragma unroll
            for (int j = 0; j < 4; ++j) b[j] = *(const bf16x8*)&Bs[j * 16 + lm][kk * 32 + lg * 8];
#pragma unroll
            for (int i = 0; i < 2; ++i)
#pragma unroll
                for (int j = 0; j < 4; ++j) acc[i][j] = MFMA16(a[i], b[j], acc[i][j]);
        }
    }

    for (int i = 0; i < 2; ++i) {
        for (int j = 0; j < 4; ++j) {
            int col = n0 + j * 16 + lm;
            float bv = bias[col];
            for (int q = 0; q < 4; ++q) {
                int row = m0 + wid * 32 + i * 16 + lg * 4 + q;
                C[(size_t)row * 1024 + col] = acc[i][j][q] + bv;
            }
        }
    }
}

// ---------------- flash attention: 8-wave block, LDS-staged K/V (best measured: R6/R9) ----------------
// Speculative exp (overlaps max-tree latency) + deferred cross-half l-sum; direct
// normalized output write (no split/combine).
// Q,K: [bh][2048][64] bf16 (Q pre-scaled); Vt: [bh][64][2048]; Out: [b][s][h*64+d] bf16.
__global__ __launch_bounds__(512, 2) void k_attn(const bf16* __restrict__ Q,
                                                 const bf16* __restrict__ Kb,
                                                 const bf16* __restrict__ Vt,
                                                 bf16* __restrict__ Out) {
    __shared__ bf16 Ks[2][64 * 64];
    __shared__ bf16 Vs[2][64 * 64];
    const int tid = threadIdx.x;
    const int wid = tid >> 6, lane = tid & 63;
    const int lm = lane & 31, hi = lane >> 5;
    const int bid = blockIdx.x;
    const int bh = bid & 31, qt = bid >> 5;   // same-bh blocks share an XCD's L2
    const int bb = bh >> 4, h = bh & 15;
    const int qrow = qt * 256 + wid * 32 + lm;
    const size_t qk_base = (size_t)bh * (2048 * 64);
    const size_t vt_base = (size_t)bh * (64 * 2048);

    // staging geometry (proven r6): LDS[row][c] = global[row][c ^ (row&7)] via source swizzle
    const int srow = tid >> 3, sc8 = tid & 7;
    const int cse = (sc8 ^ (srow & 7)) * 8;
    const bf16* kstage = Kb + qk_base + (size_t)srow * 64 + cse;     // + kt*4096
    const bf16* vstage = Vt + vt_base + (size_t)srow * 2048 + cse;   // + kt*64
    const int ldsoff = wid * 1024;

    bf16x8 qf[4];
    {
        const bf16* qp = Q + qk_base + (size_t)qrow * 64 + hi * 8;
#pragma unroll
        for (int f = 0; f < 4; ++f) qf[f] = *(const bf16x8*)(qp + f * 16);
    }

    f32x16 O0 = {}, O1 = {};
    float mrow = -1e30f, lsum = 0.f;   // lsum = this lane's half; cross-half sum deferred

    const int swz = (lm & 7);

    __builtin_amdgcn_global_load_lds(
        (const __attribute__((address_space(1))) void*)(kstage),
        (__attribute__((address_space(3))) void*)((char*)&Ks[0][0] + ldsoff), 16, 0, 0);
    __builtin_amdgcn_global_load_lds(
        (const __attribute__((address_space(1))) void*)(vstage),
        (__attribute__((address_space(3))) void*)((char*)&Vs[0][0] + ldsoff), 16, 0, 0);
    __syncthreads();

    int cur = 0;
#pragma unroll 1
    for (int kt = 0; kt < 32; ++kt) {
        if (kt + 1 < 32) {
            __builtin_amdgcn_global_load_lds(
                (const __attribute__((address_space(1))) void*)(kstage + (size_t)(kt + 1) * 4096),
                (__attribute__((address_space(3))) void*)((char*)&Ks[cur ^ 1][0] + ldsoff), 16, 0, 0);
            __builtin_amdgcn_global_load_lds(
                (const __attribute__((address_space(1))) void*)(vstage + (size_t)(kt + 1) * 64),
                (__attribute__((address_space(3))) void*)((char*)&Vs[cur ^ 1][0] + ldsoff), 16, 0, 0);
        }

        const char* Ksc = (const char*)&Ks[cur][0];
        const char* Vsc = (const char*)&Vs[cur][0];

        bf16x8 kf0[4], kf1[4];
#pragma unroll
        for (int f = 0; f < 4; ++f) {
            int ch = (f << 1) | hi;
            kf0[f] = *(const bf16x8*)(Ksc + lm * 128 + ((ch ^ swz) << 4));
            kf1[f] = *(const bf16x8*)(Ksc + (lm + 32) * 128 + ((ch ^ swz) << 4));
        }
        bf16x8 vf0[4], vf1[4];
#pragma unroll
        for (int ks = 0; ks < 4; ++ks) {
            int ch = (ks << 1) | hi;
            vf0[ks] = *(const bf16x8*)(Vsc + lm * 128 + ((ch ^ swz) << 4));
            vf1[ks] = *(const bf16x8*)(Vsc + (lm + 32) * 128 + ((ch ^ swz) << 4));
        }

        // S^T = K · Q^T
        f32x16 s0 = {}, s1 = {};
#pragma unroll
        for (int f = 0; f < 4; ++f) {
            s0 = MFMA32(kf0[f], qf[f], s0);
            s1 = MFMA32(kf1[f], qf[f], s1);
        }

        // speculative P = exp2(S - mrow_old): starts immediately, overlaps max reduction
        float pe0[16], pe1[16];
#pragma unroll
        for (int r = 0; r < 16; ++r) pe0[r] = __builtin_amdgcn_exp2f(s0[r] - mrow);
#pragma unroll
        for (int r = 0; r < 16; ++r) pe1[r] = __builtin_amdgcn_exp2f(s1[r] - mrow);

        // tile row-max (tree + cross-half swap)
        float t8[8];
#pragma unroll
        for (int r = 0; r < 8; ++r)
            t8[r] = fmaxf(fmaxf(s0[r], s0[r + 8]), fmaxf(s1[r], s1[r + 8]));
#pragma unroll
        for (int st = 4; st; st >>= 1)
#pragma unroll
            for (int r = 0; r < st; ++r) t8[r] = fmaxf(t8[r], t8[r + st]);
        float pm = swapred_max(t8[0]);

        // defer-max: rescale (and redo exp with the new max) only when max grew > 8
        if (!__all(pm <= mrow + 8.0f)) {
            float mnew = fmaxf(mrow, pm);
            float corr = __builtin_amdgcn_exp2f(mrow - mnew);
            lsum *= corr;
            O0 *= corr;
            O1 *= corr;
            mrow = mnew;
#pragma unroll
            for (int r = 0; r < 16; ++r) pe0[r] = __builtin_amdgcn_exp2f(s0[r] - mrow);
#pragma unroll
            for (int r = 0; r < 16; ++r) pe1[r] = __builtin_amdgcn_exp2f(s1[r] - mrow);
        }

        // lane-local row-sum (cross-half swap deferred to epilogue)
        float u8[8];
#pragma unroll
        for (int r = 0; r < 8; ++r) u8[r] = (pe0[r] + pe0[r + 8]) + (pe1[r] + pe1[r + 8]);
#pragma unroll
        for (int st = 4; st; st >>= 1)
#pragma unroll
            for (int r = 0; r < st; ++r) u8[r] = u8[r] + u8[r + st];
        lsum += u8[0];

        // redistribute P into PV B-frags (in-register, shfl_xor 32)
        bf16x8 pf[4];
        pack_frags(pe0, hi, pf[0], pf[1]);
        pack_frags(pe1, hi, pf[2], pf[3]);

        // O^T += Vt · P^T
#pragma unroll
        for (int ks = 0; ks < 4; ++ks) {
            O0 = MFMA32(vf0[ks], pf[ks], O0);
            O1 = MFMA32(vf1[ks], pf[ks], O1);
        }

        __syncthreads();
        cur ^= 1;
    }

    float lrow = swapred_sum(lsum);
    float inv = 1.0f / lrow;
    bf16* op = Out + ((size_t)bb * 2048 + qrow) * 1024 + h * 64 + 4 * hi;
#pragma unroll
    for (int t = 0; t < 4; ++t) {
        bf16x4 w0, w1;
#pragma unroll
        for (int e = 0; e < 4; ++e) {
            w0[e] = (bf16)(O0[4 * t + e] * inv);
            w1[e] = (bf16)(O1[4 * t + e] * inv);
        }
        *(bf16x4*)(op + 8 * t)      = w0;   // d = 4*hi + 8*t + e
        *(bf16x4*)(op + 32 + 8 * t) = w1;   // + 32
    }
}

extern "C" void kernel_launch(void* const* d_in, const int* in_sizes, int n_in,
                              void* d_out, int out_size, void* d_ws, size_t ws_size,
                              hipStream_t stream) {
    const float* q  = (const float*)d_in[0];
    const float* k  = (const float*)d_in[1];
    const float* v  = (const float*)d_in[2];
    const float* Wq = (const float*)d_in[3];
    const float* bq = (const float*)d_in[4];
    const float* Wk = (const float*)d_in[5];
    const float* bk = (const float*)d_in[6];
    const float* Wv = (const float*)d_in[7];
    const float* bv = (const float*)d_in[8];
    const float* Wo = (const float*)d_in[9];
    const float* bo = (const float*)d_in[10];

    char* ws = (char*)d_ws;
    const size_t MB = 1ull << 20;
    const dim3 twg(16, 16), blk(256);

    if (ws_size >= 40 * MB) {
        // fused path (40 MB): no cvt pass, no combine
        bf16* Wtq = (bf16*)(ws + 0 * MB);
        bf16* Wtk = (bf16*)(ws + 2 * MB);
        bf16* Wtv = (bf16*)(ws + 4 * MB);
        bf16* Wto = (bf16*)(ws + 6 * MB);
        bf16* Qb  = (bf16*)(ws + 8 * MB);
        bf16* Kb  = (bf16*)(ws + 16 * MB);
        bf16* Vtb = (bf16*)(ws + 24 * MB);
        bf16* AOb = (bf16*)(ws + 32 * MB);

        k_transpose_w4<<<dim3(16, 16, 4), blk, 0, stream>>>(Wq, Wk, Wv, Wo, Wtq, Wtk, Wtv, Wto);
        k_gemm_qkv<<<768, blk, 0, stream>>>(q, k, v, Wtq, Wtk, Wtv, bq, bk, bv, Qb, Kb, Vtb);
        k_attn<<<256, 512, 0, stream>>>(Qb, Kb, Vtb, AOb);
        k_gemm_out<<<512, blk, 0, stream>>>(AOb, Wto, bo, (float*)d_out);
    } else {
        // sequential fallback (34 MB ws)
        bf16* Wt   = (bf16*)(ws + 0 * MB);
        bf16* Qb   = (bf16*)(ws + 2 * MB);
        bf16* Kb   = (bf16*)(ws + 10 * MB);
        bf16* Vtb  = (bf16*)(ws + 18 * MB);
        bf16* AOb  = (bf16*)(ws + 26 * MB);

        k_transpose_w<<<twg, blk, 0, stream>>>(Wq, Wt, QSCL);
        k_gemm_proj<<<256, blk, 0, stream>>>(q, Wt, bq, QSCL, (void*)Qb);
        k_transpose_w<<<twg, blk, 0, stream>>>(Wk, Wt, 1.0f);
        k_gemm_proj<<<256, blk, 0, stream>>>(k, Wt, bk, 1.0f, (void*)Kb);
        k_transpose_w<<<twg, blk, 0, stream>>>(Wv, Wt, 1.0f);
        k_gemm_vt<<<256, blk, 0, stream>>>(Wt, v, bv, Vtb);
        k_transpose_w<<<twg, blk, 0, stream>>>(Wo, Wt, 1.0f);
        k_attn<<<256, 512, 0, stream>>>(Qb, Kb, Vtb, AOb);
        k_gemm_out<<<512, blk, 0, stream>>>(AOb, Wt, bo, (float*)d_out);
    }
}